// Round 5
// baseline (369.216 us; speedup 1.0000x reference)
//
#include <hip/hip_runtime.h>
#include <math.h>

// ---------------------------------------------------------------------------
// R19 = R18 with the h2a dispatch arg-count fixed (was 12 args, needs 13).
// R18: quarter-pipelined A-staging via __builtin_amdgcn_global_load_lds.
// R17's reg-staged T14 spilled (acc 128 AGPR + 108 VGPR + 44 staging > 256
// budget -> +22MB scratch traffic). DMA staging costs 0 VGPRs. Quarter = 32ch
// (324px*32ch*2B = 20736B), double-buffered = 41472B = SAME LDS as R14 ->
// 2 blocks/CU kept. Per quarter: 9 MFMA units (~3-6k cy) hide the ~900cy DMA
// of quarter q+1; barrier vmcnt-drain is then free. Rule #21: linear LDS dest,
// inverse-swizzled per-lane global source (g = p ^ (px&3)), swizzled read.
// OOB halo lanes DMA from a zeroed 32B workspace region (zeroed in wtrans6).
// ---------------------------------------------------------------------------

typedef __attribute__((ext_vector_type(8))) short bf16x8;
typedef __attribute__((ext_vector_type(4))) float f32x4;

__device__ inline float bf2f(unsigned short u) {
    unsigned v = ((unsigned)u) << 16;
    return __builtin_bit_cast(float, v);
}
__device__ inline unsigned short f2bf(float f) {
    unsigned u = __builtin_bit_cast(unsigned, f);
    u += 0x7FFF + ((u >> 16) & 1);   // RNE
    return (unsigned short)(u >> 16);
}

// ---------------- head conv: fp32 NCHW (Cin=3) -> NHWC bf16 (C=128) ---------
__global__ __launch_bounds__(256) void head_conv(
    const float* __restrict__ x, const float* __restrict__ w,
    const float* __restrict__ bias, unsigned short* __restrict__ out)
{
    __shared__ float wlds[216];          // [ci][tap][co8]
    __shared__ float tile[3][34 * 34];
    const int tid = threadIdx.x, cog = blockIdx.y, b = blockIdx.z;
    const int tile_y = (blockIdx.x >> 2) * 32, tile_x = (blockIdx.x & 3) * 32;

    if (tid < 216) {
        int co = tid & 7, rest = tid >> 3, tap = rest % 9, ci = rest / 9;
        wlds[tid] = w[((cog * 8 + co) * 3 + ci) * 9 + tap];
    }
    for (int idx = tid; idx < 3 * 34 * 34; idx += 256) {
        int ci = idx / 1156, rem = idx - ci * 1156;
        int r = rem / 34, c = rem - r * 34;
        int gy = tile_y - 1 + r, gx = tile_x - 1 + c;
        float v = 0.f;
        if ((unsigned)gy < 128u && (unsigned)gx < 128u)
            v = x[(((size_t)(b * 3 + ci)) << 14) + (gy << 7) + gx];
        tile[ci][rem] = v;
    }
    __syncthreads();

    const int ty = tid >> 4, tx = tid & 15, py = ty * 2;
    float acc[2][2][8];
    #pragma unroll
    for (int r = 0; r < 2; ++r)
        #pragma unroll
        for (int h = 0; h < 2; ++h)
            #pragma unroll
            for (int co = 0; co < 8; ++co) acc[r][h][co] = 0.f;

    #pragma unroll
    for (int ci = 0; ci < 3; ++ci) {
        #pragma unroll
        for (int ky = 0; ky < 3; ++ky) {
            #pragma unroll
            for (int kx = 0; kx < 3; ++kx) {
                const float* wp = wlds + (ci * 9 + ky * 3 + kx) * 8;
                float i00 = tile[ci][(py + ky) * 34 + tx + kx];
                float i01 = tile[ci][(py + ky) * 34 + tx + 16 + kx];
                float i10 = tile[ci][(py + 1 + ky) * 34 + tx + kx];
                float i11 = tile[ci][(py + 1 + ky) * 34 + tx + 16 + kx];
                #pragma unroll
                for (int co = 0; co < 8; ++co) {
                    float wv = wp[co];
                    acc[0][0][co] += i00 * wv;
                    acc[0][1][co] += i01 * wv;
                    acc[1][0][co] += i10 * wv;
                    acc[1][1][co] += i11 * wv;
                }
            }
        }
    }

    #pragma unroll
    for (int r = 0; r < 2; ++r) {
        #pragma unroll
        for (int h = 0; h < 2; ++h) {
            int gy = tile_y + py + r, gx = tile_x + tx + h * 16;
            bf16x8 pv;
            #pragma unroll
            for (int co = 0; co < 8; ++co)
                pv[co] = (short)f2bf(acc[r][h][co] + bias[cog * 8 + co]);
            *(bf16x8*)(out + (((((size_t)b << 14) + gy * 128 + gx)) << 7) + cog * 8) = pv;
        }
    }
}

// ---------------- main conv: implicit GEMM, bf16 MFMA -----------------------
// 16x16 px tile, 4 waves (2m x 2n for main; 4m x 1 for tail). A staged per
// 32-ch QUARTER via global_load_lds into double buffer (2 x 10368 ush).
// Quarter slot u in [0,1296): px = u>>2, slot p = u&3 holds group
// g = p ^ (px&3) (inverse-swizzled source). Read: p = lq ^ (px&3).
template <int LM, int NTW, int WNSPLIT, int DOMEAN, int TAILFUSE>
__global__ __launch_bounds__(256, 2) void conv_mfma(
    const unsigned short* __restrict__ in, const unsigned short* __restrict__ wT,
    size_t wstride, const float* __restrict__ bias, unsigned short* __restrict__ out,
    float* __restrict__ meanb, const float* __restrict__ x,
    const unsigned short* __restrict__ kb, float* __restrict__ outf,
    const unsigned short* __restrict__ zbuf, int Coutp, int Cout, int relu)
{
    __shared__ unsigned short lds[TAILFUSE ? 26624 : 20736];
    const int tid = threadIdx.x;
    const int b = blockIdx.y;
    const int row0 = (blockIdx.x >> 3) << 4;
    const int col0 = (blockIdx.x & 7) << 4;
    const int l = tid & 63, wv = tid >> 6;
    const int li = l & 15, lq = l >> 4;
    const int m_base = WNSPLIT ? (wv >> 1) * LM : wv * LM;
    const int n_base = WNSPLIT ? (wv & 1) * NTW : 0;
    const unsigned short* inb7 = in + ((size_t)b << 21);
    const unsigned short* wbase = wT + (size_t)b * wstride;

    f32x4 acc[LM][NTW];
    #pragma unroll
    for (int lm = 0; lm < LM; ++lm)
        #pragma unroll
        for (int nt = 0; nt < NTW; ++nt)
            acc[lm][nt] = (f32x4){0.f, 0.f, 0.f, 0.f};

    // Precompute per-lane DMA source offsets (quarter-invariant).
    // Issue i<5: slots [(i*4+wv)*64, +64). Issue 5 (wave 0 only): slots
    // [1232,1296) — overlaps wave 3's issue 4 with identical data (benign).
    int soff[6];
    #pragma unroll
    for (int i = 0; i < 6; ++i) {
        int base = (i < 5) ? (i * 4 + wv) * 64 : 1232;
        int u = base + l;
        int px = u >> 2, p = u & 3;
        int g = p ^ (px & 3);
        int hr = px / 18, hc = px - hr * 18;
        int gy = row0 - 1 + hr, gx = col0 - 1 + hc;
        soff[i] = ((unsigned)gy < 128u && (unsigned)gx < 128u)
                      ? ((((gy << 7) + gx) << 7) + g * 8) : -1;
    }

    auto stageQ = [&](int q) {
        unsigned short* dbuf = lds + (q & 1) * 10368;
        const int qo = q * 32;
        #pragma unroll
        for (int i = 0; i < 6; ++i) {
            if (i == 5 && wv != 0) continue;     // wave-uniform branch
            int base = (i < 5) ? (i * 4 + wv) * 64 : 1232;
            const unsigned short* src =
                (soff[i] >= 0) ? (inb7 + soff[i] + qo) : zbuf;
            __builtin_amdgcn_global_load_lds((const void*)src,
                                             (void*)(dbuf + base * 8), 16, 0, 0);
        }
    };
    auto loadB = [&](int q, bf16x8 (&dst)[NTW], int tap) {
        const unsigned short* p = wbase +
            (size_t)(tap * 4 + q) * (Coutp * 32) +
            (n_base * 16 + li) * 32 + lq * 8;
        #pragma unroll
        for (int nt = 0; nt < NTW; ++nt)
            dst[nt] = *(const bf16x8*)(p + nt * 512);
    };
    auto compute = [&](const unsigned short* lbuf, bf16x8 (&bf)[NTW], int tap) {
        int ky = tap / 3, kx = tap - ky * 3;
        #pragma unroll
        for (int lm = 0; lm < LM; ++lm) {
            int px = (m_base + lm + ky) * 18 + li + kx;
            bf16x8 af = *(const bf16x8*)(lbuf + px * 32 + ((lq ^ (px & 3)) * 8));
            #pragma unroll
            for (int nt = 0; nt < NTW; ++nt)
                acc[lm][nt] = __builtin_amdgcn_mfma_f32_16x16x32_bf16(
                    af, bf[nt], acc[lm][nt], 0, 0, 0);
        }
    };

    stageQ(0);
    __syncthreads();
    #pragma unroll
    for (int q = 0; q < 4; ++q) {
        const unsigned short* lbuf = lds + (q & 1) * 10368;
        bf16x8 bA[NTW], bB[NTW];
        loadB(q, bA, 0);
        loadB(q, bB, 1);
        if (q < 3) stageQ(q + 1);   // DMA issued after units 0-1's B-loads
        compute(lbuf, bA, 0);
        loadB(q, bA, 2);
        compute(lbuf, bB, 1);
        loadB(q, bB, 3);
        compute(lbuf, bA, 2);
        loadB(q, bA, 4);
        compute(lbuf, bB, 3);
        loadB(q, bB, 5);
        compute(lbuf, bA, 4);
        loadB(q, bA, 6);
        compute(lbuf, bB, 5);
        loadB(q, bB, 7);
        compute(lbuf, bA, 6);
        loadB(q, bA, 8);
        compute(lbuf, bB, 7);
        compute(lbuf, bA, 8);
        if (q < 3) __syncthreads();
    }

    float bv[NTW], msum[NTW];
    #pragma unroll
    for (int nt = 0; nt < NTW; ++nt) {
        int co = (n_base + nt) * 16 + li;
        bv[nt] = (co < Cout) ? bias[co] : 0.f;
        msum[nt] = 0.f;
    }

    if (TAILFUSE) {
        // ---- P (wgt) -> LDS, stride 104 ush; zero pad co 80..95 ----
        __syncthreads();
        #pragma unroll
        for (int lm = 0; lm < LM; ++lm) {
            int rowl = m_base + lm;
            #pragma unroll
            for (int r = 0; r < 4; ++r) {
                int coll = lq * 4 + r;
                #pragma unroll
                for (int nt = 0; nt < NTW; ++nt)
                    lds[(rowl * 16 + coll) * 104 + nt * 16 + li] =
                        f2bf(acc[lm][nt][r] + bv[nt]);
            }
        }
        {
            bf16x8 z = {0, 0, 0, 0, 0, 0, 0, 0};
            *(bf16x8*)(lds + tid * 104 + 80) = z;
            *(bf16x8*)(lds + tid * 104 + 88) = z;
        }
        __syncthreads();

        // ---- e-GEMM: e[px][i] = sum_co P[px][co] * kern[co][i] ----
        f32x4 eacc[4][2];
        #pragma unroll
        for (int mm = 0; mm < 4; ++mm)
            #pragma unroll
            for (int nt = 0; nt < 2; ++nt)
                eacc[mm][nt] = (f32x4){0.f, 0.f, 0.f, 0.f};
        #pragma unroll
        for (int s = 0; s < 3; ++s) {
            bf16x8 kbf[2];
            #pragma unroll
            for (int nt = 0; nt < 2; ++nt)
                kbf[nt] = *(const bf16x8*)(kb + ((s * 2 + nt) * 16 + li) * 32 + lq * 8);
            #pragma unroll
            for (int mm = 0; mm < 4; ++mm) {
                int px = (wv * 4 + mm) * 16 + li;
                bf16x8 pf = *(const bf16x8*)(lds + px * 104 + s * 32 + lq * 8);
                #pragma unroll
                for (int nt = 0; nt < 2; ++nt)
                    eacc[mm][nt] = __builtin_amdgcn_mfma_f32_16x16x32_bf16(
                        pf, kbf[nt], eacc[mm][nt], 0, 0, 0);
            }
        }
        __syncthreads();

        // ---- e (C-layout) -> LDS fp32, stride 33 ----
        float* elds = (float*)lds;
        #pragma unroll
        for (int mm = 0; mm < 4; ++mm) {
            #pragma unroll
            for (int nt = 0; nt < 2; ++nt) {
                int i = nt * 16 + li;
                if (i < 25) {
                    #pragma unroll
                    for (int r = 0; r < 4; ++r) {
                        int px = (wv * 4 + mm) * 16 + lq * 4 + r;
                        elds[px * 33 + i] = eacc[mm][nt][r];
                    }
                }
            }
        }
        __syncthreads();

        // ---- apply ----
        const int h = row0 + (tid >> 4), w = col0 + (tid & 15);
        const int pix = h * 128 + w;
        float e[25];
        #pragma unroll
        for (int i = 0; i < 25; ++i) e[i] = elds[tid * 33 + i];

        int yy[5], xx[5];
        #pragma unroll
        for (int d = 0; d < 5; ++d) {
            int y = h - 2 + d;
            yy[d] = y < 0 ? -y : (y > 127 ? 254 - y : y);
            int xv = w - 2 + d;
            xx[d] = xv < 0 ? -xv : (xv > 127 ? 254 - xv : xv);
        }
        #pragma unroll
        for (int c = 0; c < 3; ++c) {
            const float* xc = x + ((size_t)(b * 3 + c) << 14);
            float s = 0.f;
            #pragma unroll
            for (int dy = 0; dy < 5; ++dy)
                #pragma unroll
                for (int dx = 0; dx < 5; ++dx)
                    s += e[dy * 5 + dx] * xc[yy[dy] * 128 + xx[dx]];
            outf[((size_t)(b * 3 + c) << 14) + pix] = s;
        }
        return;
    }

    #pragma unroll
    for (int lm = 0; lm < LM; ++lm) {
        int row = row0 + m_base + lm;
        #pragma unroll
        for (int r = 0; r < 4; ++r) {
            int col = col0 + lq * 4 + r;
            size_t pbase = ((((size_t)b << 14) + row * 128 + col)) * (size_t)Coutp;
            #pragma unroll
            for (int nt = 0; nt < NTW; ++nt) {
                float v = acc[lm][nt][r] + bv[nt];
                if (relu) v = fmaxf(v, 0.f);
                if (DOMEAN) msum[nt] += v;
                out[pbase + (n_base + nt) * 16 + li] = f2bf(v);
            }
        }
    }
    if (DOMEAN) {
        #pragma unroll
        for (int nt = 0; nt < NTW; ++nt) {
            float t = msum[nt];
            t += __shfl_xor(t, 16, 64);
            t += __shfl_xor(t, 32, 64);
            if (lq == 0)
                atomicAdd(&meanb[b * 128 + (n_base + nt) * 16 + li], t);
        }
    }
}

// ---- weight transform: [Co][128][3][3] f32 -> [tap*4+kc][Coutp][32] bf16 ---
__device__ inline void wtrans_one(const float* w, unsigned short* wT,
                                  int Co, int Coutp, int idx)
{
    int ch = idx & 31;
    int rest = idx >> 5;
    int co = rest % Coutp;
    int slice = rest / Coutp;
    int kc = slice & 3, tap = slice >> 2;
    float v = (co < Co) ? w[((size_t)(co * 128 + kc * 32 + ch)) * 9 + tap] : 0.f;
    wT[idx] = f2bf(v);
}

__global__ __launch_bounds__(256) void wtrans6(
    const float* __restrict__ w0, const float* __restrict__ w1,
    const float* __restrict__ w2, const float* __restrict__ w3,
    const float* __restrict__ w4, const float* __restrict__ kern,
    unsigned short* __restrict__ t0, unsigned short* __restrict__ t1,
    unsigned short* __restrict__ t2, unsigned short* __restrict__ t3,
    unsigned short* __restrict__ t4, unsigned short* __restrict__ kb,
    float* __restrict__ meanz)
{
    int idx = blockIdx.x * 256 + threadIdx.x;
    int y = blockIdx.y;
    if (y < 4) {
        const float* w = y == 0 ? w0 : y == 1 ? w1 : y == 2 ? w2 : w3;
        unsigned short* t = y == 0 ? t0 : y == 1 ? t1 : y == 2 ? t2 : t3;
        wtrans_one(w, t, 128, 128, idx);
    } else if (y == 4) {
        if (idx < 9 * 4 * 80 * 32) wtrans_one(w4, t4, 72, 80, idx);
    } else {
        if (idx < 3072) {
            int lq = (idx & 31) >> 3, j = idx & 7;
            int row = idx >> 5;
            int li = row & 15, snt = row >> 4;
            int s = snt >> 1, nt = snt & 1;
            int co = s * 32 + lq * 8 + j, i = nt * 16 + li;
            float v = (co < 72 && i < 25) ? kern[co * 25 + i] : 0.f;
            kb[idx] = f2bf(v);
        }
        if (idx < 2112) meanz[idx] = 0.f;   // mean1+mean2+zbuf (no memset)
    }
}

// ---- SE FC + per-batch scaled weight copy, fused ---------------------------
__global__ __launch_bounds__(256) void wscale8f(
    const unsigned short* __restrict__ wT, const float* __restrict__ meanb,
    const float* __restrict__ w1, const float* __restrict__ b1,
    const float* __restrict__ w2, const float* __restrict__ b2,
    unsigned short* __restrict__ out, int Coutp)
{
    const int b = blockIdx.y, c = threadIdx.x;
    __shared__ float h1[8];
    __shared__ float sl[128];
    if (c < 8) {
        float s = 0.f;
        for (int j = 0; j < 128; ++j) s += w1[c * 128 + j] * meanb[b * 128 + j];
        h1[c] = fmaxf(s * (1.f / 16384.f) + b1[c], 0.f);
    }
    __syncthreads();
    if (c < 128) {
        float s = b2[c];
        #pragma unroll
        for (int j = 0; j < 8; ++j) s += w2[c * 8 + j] * h1[j];
        sl[c] = 1.f / (1.f + expf(-s));
    }
    __syncthreads();
    int r = blockIdx.x * 256 + c;
    int ch = r & 31;
    int kc = ((r >> 5) / Coutp) & 3;
    out[(size_t)b * (9 * 4 * Coutp * 32) + r] = f2bf(bf2f(wT[r]) * sl[kc * 32 + ch]);
}

// ---------------------------------------------------------------------------
extern "C" void kernel_launch(void* const* d_in, const int* in_sizes, int n_in,
                              void* d_out, int out_size, void* d_ws, size_t ws_size,
                              hipStream_t stream)
{
    const float* x      = (const float*)d_in[0];
    const float* w_head = (const float*)d_in[1];
    const float* b_head = (const float*)d_in[2];
    const float* w_h1a  = (const float*)d_in[3];
    const float* b_h1a  = (const float*)d_in[4];
    const float* w_h1b  = (const float*)d_in[5];
    const float* b_h1b  = (const float*)d_in[6];
    const float* du1_w1 = (const float*)d_in[7];
    const float* du1_b1 = (const float*)d_in[8];
    const float* du1_w2 = (const float*)d_in[9];
    const float* du1_b2 = (const float*)d_in[10];
    const float* w_h2a  = (const float*)d_in[11];
    const float* b_h2a  = (const float*)d_in[12];
    const float* w_h2b  = (const float*)d_in[13];
    const float* b_h2b  = (const float*)d_in[14];
    const float* du2_w1 = (const float*)d_in[15];
    const float* du2_b1 = (const float*)d_in[16];
    const float* du2_w2 = (const float*)d_in[17];
    const float* du2_b2 = (const float*)d_in[18];
    const float* w_tail = (const float*)d_in[19];
    const float* b_tail = (const float*)d_in[20];
    const float* kern   = (const float*)d_in[21];
    float* out = (float*)d_out;

    unsigned short* fb0  = (unsigned short*)d_ws;        // 16,777,216 elems
    unsigned short* fb1  = fb0 + 16777216;
    unsigned short* wt1  = fb1 + 16777216;               // 147456 each
    unsigned short* wt2  = wt1 + 147456;
    unsigned short* wt3  = wt2 + 147456;
    unsigned short* wt4  = wt3 + 147456;
    unsigned short* wtt  = wt4 + 147456;                 // 92160
    unsigned short* wsa  = wtt + 92160;                  // 8x scaled h2a weights
    unsigned short* wst  = wsa + 8 * 147456;             // 8x scaled tail weights
    unsigned short* kbb  = wst + 8 * 92160;              // 3072 (kern B-frag)
    float* mean1  = (float*)(kbb + 3072);                // 1024
    float* mean2  = mean1 + 1024;
    unsigned short* zbuf = (unsigned short*)(mean2 + 1024);  // 64 zeroed floats

    dim3 blk(256);
    // wtrans6 zeroes mean1+mean2+zbuf (y==5 branch) — no memset dispatch
    wtrans6<<<dim3(576, 6), blk, 0, stream>>>(w_h1a, w_h1b, w_h2a, w_h2b, w_tail,
                                              kern, wt1, wt2, wt3, wt4, wtt, kbb,
                                              mean1);

    head_conv<<<dim3(16, 16, 8), blk, 0, stream>>>(x, w_head, b_head, fb0);

    dim3 cgrid(64, 8);   // 512 blocks: 64 tiles/batch x 8 batches
    conv_mfma<8, 4, 1, 0, 0><<<cgrid, blk, 0, stream>>>(
        fb0, wt1, 0, b_h1a, fb1, nullptr, nullptr, nullptr, nullptr, zbuf, 128, 128, 1);
    conv_mfma<8, 4, 1, 1, 0><<<cgrid, blk, 0, stream>>>(
        fb1, wt2, 0, b_h1b, fb0, mean1, nullptr, nullptr, nullptr, zbuf, 128, 128, 1);

    wscale8f<<<dim3(576, 8), blk, 0, stream>>>(wt3, mean1, du1_w1, du1_b1,
                                               du1_w2, du1_b2, wsa, 128);

    conv_mfma<8, 4, 1, 0, 0><<<cgrid, blk, 0, stream>>>(
        fb0, wsa, 147456, b_h2a, fb1, nullptr, nullptr, nullptr, nullptr, zbuf, 128, 128, 1);
    conv_mfma<8, 4, 1, 1, 0><<<cgrid, blk, 0, stream>>>(
        fb1, wt4, 0, b_h2b, fb0, mean2, nullptr, nullptr, nullptr, zbuf, 128, 128, 1);

    wscale8f<<<dim3(360, 8), blk, 0, stream>>>(wtt, mean2, du2_w1, du2_b1,
                                               du2_w2, du2_b2, wst, 80);

    // tail conv + fused dynamic filter via MFMA e-GEMM (writes final output)
    conv_mfma<4, 5, 0, 0, 1><<<cgrid, blk, 0, stream>>>(
        fb0, wst, 92160, b_tail, nullptr, nullptr, x, kbb, out, zbuf, 80, 72, 0);
}

// Round 6
// 346.798 us; speedup vs baseline: 1.0646x; 1.0646x over previous
//
#include <hip/hip_runtime.h>
#include <math.h>

// ---------------------------------------------------------------------------
// R20 = R14 base + (1) XCD-batch affinity swizzle: flat grid 512, b=bid&7,
// tile=bid>>3 -> each XCD serves ONE batch (B working set 2.3MB->288KB/XCD,
// L3-latency B loads become L2 hits), + (2) B prefetch depth 2 (3 rotating
// named bufs, +8 VGPR). R19 refuted: 64B/px quarter staging is below the
// 128B line granularity -> 2x HBM fetch + broken write-combining (FETCH 19->51,
// WRITE 33->73MB). A-staging must stay at >=128B/px per temporal burst (R14
// halves). DMA/reg-prefetch of A both closed (R17 spill, R19 granularity).
// ---------------------------------------------------------------------------

typedef __attribute__((ext_vector_type(8))) short bf16x8;
typedef __attribute__((ext_vector_type(4))) float f32x4;

__device__ inline float bf2f(unsigned short u) {
    unsigned v = ((unsigned)u) << 16;
    return __builtin_bit_cast(float, v);
}
__device__ inline unsigned short f2bf(float f) {
    unsigned u = __builtin_bit_cast(unsigned, f);
    u += 0x7FFF + ((u >> 16) & 1);   // RNE
    return (unsigned short)(u >> 16);
}

// ---------------- head conv: fp32 NCHW (Cin=3) -> NHWC bf16 (C=128) ---------
__global__ __launch_bounds__(256) void head_conv(
    const float* __restrict__ x, const float* __restrict__ w,
    const float* __restrict__ bias, unsigned short* __restrict__ out)
{
    __shared__ float wlds[216];          // [ci][tap][co8]
    __shared__ float tile[3][34 * 34];
    const int tid = threadIdx.x, cog = blockIdx.y, b = blockIdx.z;
    const int tile_y = (blockIdx.x >> 2) * 32, tile_x = (blockIdx.x & 3) * 32;

    if (tid < 216) {
        int co = tid & 7, rest = tid >> 3, tap = rest % 9, ci = rest / 9;
        wlds[tid] = w[((cog * 8 + co) * 3 + ci) * 9 + tap];
    }
    for (int idx = tid; idx < 3 * 34 * 34; idx += 256) {
        int ci = idx / 1156, rem = idx - ci * 1156;
        int r = rem / 34, c = rem - r * 34;
        int gy = tile_y - 1 + r, gx = tile_x - 1 + c;
        float v = 0.f;
        if ((unsigned)gy < 128u && (unsigned)gx < 128u)
            v = x[(((size_t)(b * 3 + ci)) << 14) + (gy << 7) + gx];
        tile[ci][rem] = v;
    }
    __syncthreads();

    const int ty = tid >> 4, tx = tid & 15, py = ty * 2;
    float acc[2][2][8];
    #pragma unroll
    for (int r = 0; r < 2; ++r)
        #pragma unroll
        for (int h = 0; h < 2; ++h)
            #pragma unroll
            for (int co = 0; co < 8; ++co) acc[r][h][co] = 0.f;

    #pragma unroll
    for (int ci = 0; ci < 3; ++ci) {
        #pragma unroll
        for (int ky = 0; ky < 3; ++ky) {
            #pragma unroll
            for (int kx = 0; kx < 3; ++kx) {
                const float* wp = wlds + (ci * 9 + ky * 3 + kx) * 8;
                float i00 = tile[ci][(py + ky) * 34 + tx + kx];
                float i01 = tile[ci][(py + ky) * 34 + tx + 16 + kx];
                float i10 = tile[ci][(py + 1 + ky) * 34 + tx + kx];
                float i11 = tile[ci][(py + 1 + ky) * 34 + tx + 16 + kx];
                #pragma unroll
                for (int co = 0; co < 8; ++co) {
                    float wv = wp[co];
                    acc[0][0][co] += i00 * wv;
                    acc[0][1][co] += i01 * wv;
                    acc[1][0][co] += i10 * wv;
                    acc[1][1][co] += i11 * wv;
                }
            }
        }
    }

    #pragma unroll
    for (int r = 0; r < 2; ++r) {
        #pragma unroll
        for (int h = 0; h < 2; ++h) {
            int gy = tile_y + py + r, gx = tile_x + tx + h * 16;
            bf16x8 pv;
            #pragma unroll
            for (int co = 0; co < 8; ++co)
                pv[co] = (short)f2bf(acc[r][h][co] + bias[cog * 8 + co]);
            *(bf16x8*)(out + (((((size_t)b << 14) + gy * 128 + gx)) << 7) + cog * 8) = pv;
        }
    }
}

// ---------------- main conv: implicit GEMM, bf16 MFMA -----------------------
// Block: 16x16 px tile; A staged in two 64-ch halves, UNPADDED stride 64 ush
// with XOR swizzle (channel-group p = g ^ (px&7)) -> conflict-free b128 reads.
// WNSPLIT=1: 4 waves tile 2 m-groups x 2 n-groups (LM=8, NTW=4 for 128 co).
// R20: flat 512 grid, b = bid&7 (XCD-batch affinity), tile = bid>>3;
// B double->triple buffered (depth-2 prefetch).
template <int LM, int NTW, int WNSPLIT, int DOMEAN, int TAILFUSE>
__global__ __launch_bounds__(256, 2) void conv_mfma(
    const unsigned short* __restrict__ in, const unsigned short* __restrict__ wT,
    size_t wstride, const float* __restrict__ bias, unsigned short* __restrict__ out,
    float* __restrict__ meanb, const float* __restrict__ x,
    const unsigned short* __restrict__ kb, float* __restrict__ outf,
    int Coutp, int Cout, int relu)
{
    __shared__ unsigned short lds[TAILFUSE ? 26624 : 20736];
    const int tid = threadIdx.x;
    const int b = blockIdx.x & 7;          // XCD affinity: batch <-> XCD
    const int tile = blockIdx.x >> 3;
    const int row0 = (tile >> 3) << 4;
    const int col0 = (tile & 7) << 4;
    const int l = tid & 63, wv = tid >> 6;
    const int li = l & 15, lq = l >> 4;
    const int m_base = WNSPLIT ? (wv >> 1) * LM : wv * LM;
    const int n_base = WNSPLIT ? (wv & 1) * NTW : 0;
    const size_t inb = ((size_t)b) << 14;
    const unsigned short* wbase = wT + (size_t)b * wstride;

    f32x4 acc[LM][NTW];
    #pragma unroll
    for (int lm = 0; lm < LM; ++lm)
        #pragma unroll
        for (int nt = 0; nt < NTW; ++nt)
            acc[lm][nt] = (f32x4){0.f, 0.f, 0.f, 0.f};

    #pragma unroll 1
    for (int half = 0; half < 2; ++half) {
        __syncthreads();
        for (int u = tid; u < 2592; u += 256) {   // 324 px * 8 ch-groups
            int px = u >> 3, g = u & 7;
            int hr = px / 18, hc = px - hr * 18;
            int gy = row0 - 1 + hr, gx = col0 - 1 + hc;
            bf16x8 v = {0, 0, 0, 0, 0, 0, 0, 0};
            if ((unsigned)gy < 128u && (unsigned)gx < 128u)
                v = *(const bf16x8*)(in + ((inb + (gy << 7) + gx) << 7) + half * 64 + g * 8);
            int p = g ^ (px & 7);                 // XOR swizzle
            *(bf16x8*)(lds + px * 64 + p * 8) = v;
        }
        __syncthreads();

        auto loadB = [&](bf16x8 (&dst)[NTW], int s) {
            int tap = s >> 1, kcl = s & 1;
            const unsigned short* p = wbase +
                (size_t)(tap * 4 + half * 2 + kcl) * (Coutp * 32) +
                (n_base * 16 + li) * 32 + lq * 8;
            #pragma unroll
            for (int nt = 0; nt < NTW; ++nt)
                dst[nt] = *(const bf16x8*)(p + nt * 512);
        };
        auto compute = [&](bf16x8 (&bf)[NTW], int s) {
            int tap = s >> 1, kcl = s & 1;
            int ky = tap / 3, kx = tap - ky * 3;
            int g = kcl * 4 + lq;
            #pragma unroll
            for (int lm = 0; lm < LM; ++lm) {
                int px = (m_base + lm + ky) * 18 + li + kx;
                bf16x8 af = *(const bf16x8*)(lds + px * 64 + ((g ^ (px & 7)) * 8));
                #pragma unroll
                for (int nt = 0; nt < NTW; ++nt)
                    acc[lm][nt] = __builtin_amdgcn_mfma_f32_16x16x32_bf16(
                        af, bf[nt], acc[lm][nt], 0, 0, 0);
            }
        };

        // depth-2 B prefetch: three named rotating buffers (rule #20: no
        // runtime-indexed vector arrays)
        bf16x8 bA[NTW], bB[NTW], bC[NTW];
        loadB(bA, 0);
        loadB(bB, 1);
        #pragma unroll 1
        for (int it = 0; it < 18; it += 3) {
            loadB(bC, it + 2);
            compute(bA, it);
            loadB(bA, it + 3 < 18 ? it + 3 : 17);
            compute(bB, it + 1);
            loadB(bB, it + 4 < 18 ? it + 4 : 17);
            compute(bC, it + 2);
        }
    }

    float bv[NTW], msum[NTW];
    #pragma unroll
    for (int nt = 0; nt < NTW; ++nt) {
        int co = (n_base + nt) * 16 + li;
        bv[nt] = (co < Cout) ? bias[co] : 0.f;
        msum[nt] = 0.f;
    }

    if (TAILFUSE) {
        // ---- P (wgt) -> LDS, stride 104 ush; zero pad co 80..95 ----
        __syncthreads();
        #pragma unroll
        for (int lm = 0; lm < LM; ++lm) {
            int rowl = m_base + lm;
            #pragma unroll
            for (int r = 0; r < 4; ++r) {
                int coll = lq * 4 + r;
                #pragma unroll
                for (int nt = 0; nt < NTW; ++nt)
                    lds[(rowl * 16 + coll) * 104 + nt * 16 + li] =
                        f2bf(acc[lm][nt][r] + bv[nt]);
            }
        }
        {
            bf16x8 z = {0, 0, 0, 0, 0, 0, 0, 0};
            *(bf16x8*)(lds + tid * 104 + 80) = z;
            *(bf16x8*)(lds + tid * 104 + 88) = z;
        }
        __syncthreads();

        // ---- e-GEMM: e[px][i] = sum_co P[px][co] * kern[co][i] ----
        f32x4 eacc[4][2];
        #pragma unroll
        for (int mm = 0; mm < 4; ++mm)
            #pragma unroll
            for (int nt = 0; nt < 2; ++nt)
                eacc[mm][nt] = (f32x4){0.f, 0.f, 0.f, 0.f};
        #pragma unroll
        for (int s = 0; s < 3; ++s) {
            bf16x8 kbf[2];
            #pragma unroll
            for (int nt = 0; nt < 2; ++nt)
                kbf[nt] = *(const bf16x8*)(kb + ((s * 2 + nt) * 16 + li) * 32 + lq * 8);
            #pragma unroll
            for (int mm = 0; mm < 4; ++mm) {
                int px = (wv * 4 + mm) * 16 + li;
                bf16x8 pf = *(const bf16x8*)(lds + px * 104 + s * 32 + lq * 8);
                #pragma unroll
                for (int nt = 0; nt < 2; ++nt)
                    eacc[mm][nt] = __builtin_amdgcn_mfma_f32_16x16x32_bf16(
                        pf, kbf[nt], eacc[mm][nt], 0, 0, 0);
            }
        }
        __syncthreads();

        // ---- e (C-layout) -> LDS fp32, stride 33 ----
        float* elds = (float*)lds;
        #pragma unroll
        for (int mm = 0; mm < 4; ++mm) {
            #pragma unroll
            for (int nt = 0; nt < 2; ++nt) {
                int i = nt * 16 + li;
                if (i < 25) {
                    #pragma unroll
                    for (int r = 0; r < 4; ++r) {
                        int px = (wv * 4 + mm) * 16 + lq * 4 + r;
                        elds[px * 33 + i] = eacc[mm][nt][r];
                    }
                }
            }
        }
        __syncthreads();

        // ---- apply ----
        const int h = row0 + (tid >> 4), w = col0 + (tid & 15);
        const int pix = h * 128 + w;
        float e[25];
        #pragma unroll
        for (int i = 0; i < 25; ++i) e[i] = elds[tid * 33 + i];

        int yy[5], xx[5];
        #pragma unroll
        for (int d = 0; d < 5; ++d) {
            int y = h - 2 + d;
            yy[d] = y < 0 ? -y : (y > 127 ? 254 - y : y);
            int xv = w - 2 + d;
            xx[d] = xv < 0 ? -xv : (xv > 127 ? 254 - xv : xv);
        }
        #pragma unroll
        for (int c = 0; c < 3; ++c) {
            const float* xc = x + ((size_t)(b * 3 + c) << 14);
            float s = 0.f;
            #pragma unroll
            for (int dy = 0; dy < 5; ++dy)
                #pragma unroll
                for (int dx = 0; dx < 5; ++dx)
                    s += e[dy * 5 + dx] * xc[yy[dy] * 128 + xx[dx]];
            outf[((size_t)(b * 3 + c) << 14) + pix] = s;
        }
        return;
    }

    #pragma unroll
    for (int lm = 0; lm < LM; ++lm) {
        int row = row0 + m_base + lm;
        #pragma unroll
        for (int r = 0; r < 4; ++r) {
            int col = col0 + lq * 4 + r;
            size_t pbase = (inb + row * 128 + col) * (size_t)Coutp;
            #pragma unroll
            for (int nt = 0; nt < NTW; ++nt) {
                float v = acc[lm][nt][r] + bv[nt];
                if (relu) v = fmaxf(v, 0.f);
                if (DOMEAN) msum[nt] += v;
                out[pbase + (n_base + nt) * 16 + li] = f2bf(v);
            }
        }
    }
    if (DOMEAN) {
        #pragma unroll
        for (int nt = 0; nt < NTW; ++nt) {
            float t = msum[nt];
            t += __shfl_xor(t, 16, 64);
            t += __shfl_xor(t, 32, 64);
            if (lq == 0)
                atomicAdd(&meanb[b * 128 + (n_base + nt) * 16 + li], t);
        }
    }
}

// ---- weight transform: [Co][128][3][3] f32 -> [tap*4+kc][Coutp][32] bf16 ---
__device__ inline void wtrans_one(const float* w, unsigned short* wT,
                                  int Co, int Coutp, int idx)
{
    int ch = idx & 31;
    int rest = idx >> 5;
    int co = rest % Coutp;
    int slice = rest / Coutp;
    int kc = slice & 3, tap = slice >> 2;
    float v = (co < Co) ? w[((size_t)(co * 128 + kc * 32 + ch)) * 9 + tap] : 0.f;
    wT[idx] = f2bf(v);
}

__global__ __launch_bounds__(256) void wtrans6(
    const float* __restrict__ w0, const float* __restrict__ w1,
    const float* __restrict__ w2, const float* __restrict__ w3,
    const float* __restrict__ w4, const float* __restrict__ kern,
    unsigned short* __restrict__ t0, unsigned short* __restrict__ t1,
    unsigned short* __restrict__ t2, unsigned short* __restrict__ t3,
    unsigned short* __restrict__ t4, unsigned short* __restrict__ kb,
    float* __restrict__ meanz)
{
    int idx = blockIdx.x * 256 + threadIdx.x;
    int y = blockIdx.y;
    if (y < 4) {
        const float* w = y == 0 ? w0 : y == 1 ? w1 : y == 2 ? w2 : w3;
        unsigned short* t = y == 0 ? t0 : y == 1 ? t1 : y == 2 ? t2 : t3;
        wtrans_one(w, t, 128, 128, idx);
    } else if (y == 4) {
        if (idx < 9 * 4 * 80 * 32) wtrans_one(w4, t4, 72, 80, idx);
    } else {
        if (idx < 3072) {
            int lq = (idx & 31) >> 3, j = idx & 7;
            int row = idx >> 5;
            int li = row & 15, snt = row >> 4;
            int s = snt >> 1, nt = snt & 1;
            int co = s * 32 + lq * 8 + j, i = nt * 16 + li;
            float v = (co < 72 && i < 25) ? kern[co * 25 + i] : 0.f;
            kb[idx] = f2bf(v);
        }
        if (idx < 2048) meanz[idx] = 0.f;   // zero mean1+mean2 (replaces memset)
    }
}

// ---- SE FC + per-batch scaled weight copy, fused ---------------------------
__global__ __launch_bounds__(256) void wscale8f(
    const unsigned short* __restrict__ wT, const float* __restrict__ meanb,
    const float* __restrict__ w1, const float* __restrict__ b1,
    const float* __restrict__ w2, const float* __restrict__ b2,
    unsigned short* __restrict__ out, int Coutp)
{
    const int b = blockIdx.y, c = threadIdx.x;
    __shared__ float h1[8];
    __shared__ float sl[128];
    if (c < 8) {
        float s = 0.f;
        for (int j = 0; j < 128; ++j) s += w1[c * 128 + j] * meanb[b * 128 + j];
        h1[c] = fmaxf(s * (1.f / 16384.f) + b1[c], 0.f);
    }
    __syncthreads();
    if (c < 128) {
        float s = b2[c];
        #pragma unroll
        for (int j = 0; j < 8; ++j) s += w2[c * 8 + j] * h1[j];
        sl[c] = 1.f / (1.f + expf(-s));
    }
    __syncthreads();
    int r = blockIdx.x * 256 + c;
    int ch = r & 31;
    int kc = ((r >> 5) / Coutp) & 3;
    out[(size_t)b * (9 * 4 * Coutp * 32) + r] = f2bf(bf2f(wT[r]) * sl[kc * 32 + ch]);
}

// ---------------------------------------------------------------------------
extern "C" void kernel_launch(void* const* d_in, const int* in_sizes, int n_in,
                              void* d_out, int out_size, void* d_ws, size_t ws_size,
                              hipStream_t stream)
{
    const float* x      = (const float*)d_in[0];
    const float* w_head = (const float*)d_in[1];
    const float* b_head = (const float*)d_in[2];
    const float* w_h1a  = (const float*)d_in[3];
    const float* b_h1a  = (const float*)d_in[4];
    const float* w_h1b  = (const float*)d_in[5];
    const float* b_h1b  = (const float*)d_in[6];
    const float* du1_w1 = (const float*)d_in[7];
    const float* du1_b1 = (const float*)d_in[8];
    const float* du1_w2 = (const float*)d_in[9];
    const float* du1_b2 = (const float*)d_in[10];
    const float* w_h2a  = (const float*)d_in[11];
    const float* b_h2a  = (const float*)d_in[12];
    const float* w_h2b  = (const float*)d_in[13];
    const float* b_h2b  = (const float*)d_in[14];
    const float* du2_w1 = (const float*)d_in[15];
    const float* du2_b1 = (const float*)d_in[16];
    const float* du2_w2 = (const float*)d_in[17];
    const float* du2_b2 = (const float*)d_in[18];
    const float* w_tail = (const float*)d_in[19];
    const float* b_tail = (const float*)d_in[20];
    const float* kern   = (const float*)d_in[21];
    float* out = (float*)d_out;

    unsigned short* fb0  = (unsigned short*)d_ws;        // 16,777,216 elems
    unsigned short* fb1  = fb0 + 16777216;
    unsigned short* wt1  = fb1 + 16777216;               // 147456 each
    unsigned short* wt2  = wt1 + 147456;
    unsigned short* wt3  = wt2 + 147456;
    unsigned short* wt4  = wt3 + 147456;
    unsigned short* wtt  = wt4 + 147456;                 // 92160
    unsigned short* wsa  = wtt + 92160;                  // 8x scaled h2a weights
    unsigned short* wst  = wsa + 8 * 147456;             // 8x scaled tail weights
    unsigned short* kbb  = wst + 8 * 92160;              // 3072 (kern B-frag)
    float* mean1  = (float*)(kbb + 3072);                // 1024
    float* mean2  = mean1 + 1024;

    dim3 blk(256);
    // wtrans6 also zeroes mean1+mean2 (y==5 branch) — no memset dispatch
    wtrans6<<<dim3(576, 6), blk, 0, stream>>>(w_h1a, w_h1b, w_h2a, w_h2b, w_tail,
                                              kern, wt1, wt2, wt3, wt4, wtt, kbb,
                                              mean1);

    head_conv<<<dim3(16, 16, 8), blk, 0, stream>>>(x, w_head, b_head, fb0);

    dim3 cgrid(512);   // flat: b = bid&7 (XCD affinity), tile = bid>>3
    conv_mfma<8, 4, 1, 0, 0><<<cgrid, blk, 0, stream>>>(
        fb0, wt1, 0, b_h1a, fb1, nullptr, nullptr, nullptr, nullptr, 128, 128, 1);
    conv_mfma<8, 4, 1, 1, 0><<<cgrid, blk, 0, stream>>>(
        fb1, wt2, 0, b_h1b, fb0, mean1, nullptr, nullptr, nullptr, 128, 128, 1);

    wscale8f<<<dim3(576, 8), blk, 0, stream>>>(wt3, mean1, du1_w1, du1_b1,
                                               du1_w2, du1_b2, wsa, 128);

    conv_mfma<8, 4, 1, 0, 0><<<cgrid, blk, 0, stream>>>(
        fb0, wsa, 147456, b_h2a, fb1, nullptr, nullptr, nullptr, nullptr, 128, 128, 1);
    conv_mfma<8, 4, 1, 1, 0><<<cgrid, blk, 0, stream>>>(
        fb1, wt4, 0, b_h2b, fb0, mean2, nullptr, nullptr, nullptr, 128, 128, 1);

    wscale8f<<<dim3(360, 8), blk, 0, stream>>>(wtt, mean2, du2_w1, du2_b1,
                                               du2_w2, du2_b2, wst, 80);

    // tail conv + fused dynamic filter via MFMA e-GEMM (writes final output)
    conv_mfma<4, 5, 0, 0, 1><<<cgrid, blk, 0, stream>>>(
        fb0, wst, 92160, b_tail, nullptr, nullptr, x, kbb, out, 80, 72, 0);
}

// Round 7
// 331.732 us; speedup vs baseline: 1.1130x; 1.0454x over previous
//
#include <hip/hip_runtime.h>
#include <math.h>

// ---------------------------------------------------------------------------
// R21: conv_mfma K-loop reverted BYTE-EXACT to R14 (4-for-4: every inner-loop
// perturbation regressed 10-20%; R20's FETCH drop proved locality wasn't the
// stall). New: attack the ~100us aux pool instead.
//  (1) SE scale moved from weights to staged A (conv(s*f,W)==conv(f,W*s)):
//      sl[128] computed in a per-block prologue, applied during A staging
//      (g=tid&7 is thread-invariant -> 8 scale regs/half). Deletes BOTH
//      wscale8f dispatches + 8x per-batch weight copies; wt3/wtt batch-shared.
//  (2) head_conv + wtrans6 merged into one flat-grid 'prep' dispatch.
//  Dispatches 9 -> 6.
// ---------------------------------------------------------------------------

typedef __attribute__((ext_vector_type(8))) short bf16x8;
typedef __attribute__((ext_vector_type(4))) float f32x4;

__device__ inline float bf2f(unsigned short u) {
    unsigned v = ((unsigned)u) << 16;
    return __builtin_bit_cast(float, v);
}
__device__ inline unsigned short f2bf(float f) {
    unsigned u = __builtin_bit_cast(unsigned, f);
    u += 0x7FFF + ((u >> 16) & 1);   // RNE
    return (unsigned short)(u >> 16);
}

// ---- weight transform helper: [Co][128][3][3] f32 -> [tap*4+kc][Coutp][32] -
__device__ inline void wtrans_one(const float* w, unsigned short* wT,
                                  int Co, int Coutp, int idx)
{
    int ch = idx & 31;
    int rest = idx >> 5;
    int co = rest % Coutp;
    int slice = rest / Coutp;
    int kc = slice & 3, tap = slice >> 2;
    float v = (co < Co) ? w[((size_t)(co * 128 + kc * 32 + ch)) * 9 + tap] : 0.f;
    wT[idx] = f2bf(v);
}

// ---------------- prep: head conv (bid<2048) + weight transforms ------------
__global__ __launch_bounds__(256) void prep(
    const float* __restrict__ x, const float* __restrict__ wh,
    const float* __restrict__ bh, unsigned short* __restrict__ fb0,
    const float* __restrict__ w0, const float* __restrict__ w1,
    const float* __restrict__ w2, const float* __restrict__ w3,
    const float* __restrict__ w4, const float* __restrict__ kern,
    unsigned short* __restrict__ t0, unsigned short* __restrict__ t1,
    unsigned short* __restrict__ t2, unsigned short* __restrict__ t3,
    unsigned short* __restrict__ t4, unsigned short* __restrict__ kb,
    float* __restrict__ meanz)
{
    __shared__ float wlds[216];          // [ci][tap][co8]
    __shared__ float tile[3][34 * 34];
    const int tid = threadIdx.x;
    const int bid = blockIdx.x;

    if (bid >= 2048) {                   // ---- weight-transform blocks ----
        int r = bid - 2048;              // 0..3455
        int y = r / 576;
        int idx = (r - y * 576) * 256 + tid;
        if (y < 4) {
            const float* w = y == 0 ? w0 : y == 1 ? w1 : y == 2 ? w2 : w3;
            unsigned short* t = y == 0 ? t0 : y == 1 ? t1 : y == 2 ? t2 : t3;
            wtrans_one(w, t, 128, 128, idx);
        } else if (y == 4) {
            if (idx < 9 * 4 * 80 * 32) wtrans_one(w4, t4, 72, 80, idx);
        } else {
            if (idx < 3072) {
                int lq = (idx & 31) >> 3, j = idx & 7;
                int row = idx >> 5;
                int li = row & 15, snt = row >> 4;
                int s = snt >> 1, nt = snt & 1;
                int co = s * 32 + lq * 8 + j, i = nt * 16 + li;
                float v = (co < 72 && i < 25) ? kern[co * 25 + i] : 0.f;
                kb[idx] = f2bf(v);
            }
            if (idx < 2048) meanz[idx] = 0.f;   // zero mean1+mean2
        }
        return;
    }

    // ---- head conv: bid = bx + 16*cog + 256*b ----
    const int bx = bid & 15, cog = (bid >> 4) & 15, b = bid >> 8;
    const int tile_y = (bx >> 2) * 32, tile_x = (bx & 3) * 32;

    if (tid < 216) {
        int co = tid & 7, rest = tid >> 3, tap = rest % 9, ci = rest / 9;
        wlds[tid] = wh[((cog * 8 + co) * 3 + ci) * 9 + tap];
    }
    for (int idx = tid; idx < 3 * 34 * 34; idx += 256) {
        int ci = idx / 1156, rem = idx - ci * 1156;
        int rr = rem / 34, c = rem - rr * 34;
        int gy = tile_y - 1 + rr, gx = tile_x - 1 + c;
        float v = 0.f;
        if ((unsigned)gy < 128u && (unsigned)gx < 128u)
            v = x[(((size_t)(b * 3 + ci)) << 14) + (gy << 7) + gx];
        tile[ci][rem] = v;
    }
    __syncthreads();

    const int ty = tid >> 4, tx = tid & 15, py = ty * 2;
    float acc[2][2][8];
    #pragma unroll
    for (int r = 0; r < 2; ++r)
        #pragma unroll
        for (int h = 0; h < 2; ++h)
            #pragma unroll
            for (int co = 0; co < 8; ++co) acc[r][h][co] = 0.f;

    #pragma unroll
    for (int ci = 0; ci < 3; ++ci) {
        #pragma unroll
        for (int ky = 0; ky < 3; ++ky) {
            #pragma unroll
            for (int kx = 0; kx < 3; ++kx) {
                const float* wp = wlds + (ci * 9 + ky * 3 + kx) * 8;
                float i00 = tile[ci][(py + ky) * 34 + tx + kx];
                float i01 = tile[ci][(py + ky) * 34 + tx + 16 + kx];
                float i10 = tile[ci][(py + 1 + ky) * 34 + tx + kx];
                float i11 = tile[ci][(py + 1 + ky) * 34 + tx + 16 + kx];
                #pragma unroll
                for (int co = 0; co < 8; ++co) {
                    float wv = wp[co];
                    acc[0][0][co] += i00 * wv;
                    acc[0][1][co] += i01 * wv;
                    acc[1][0][co] += i10 * wv;
                    acc[1][1][co] += i11 * wv;
                }
            }
        }
    }

    #pragma unroll
    for (int r = 0; r < 2; ++r) {
        #pragma unroll
        for (int h = 0; h < 2; ++h) {
            int gy = tile_y + py + r, gx = tile_x + tx + h * 16;
            bf16x8 pv;
            #pragma unroll
            for (int co = 0; co < 8; ++co)
                pv[co] = (short)f2bf(acc[r][h][co] + bh[cog * 8 + co]);
            *(bf16x8*)(fb0 + (((((size_t)b << 14) + gy * 128 + gx)) << 7) + cog * 8) = pv;
        }
    }
}

// ---------------- main conv: implicit GEMM, bf16 MFMA (R14 K-loop) ----------
// Block: 16x16 px tile; A staged in two 64-ch halves, UNPADDED stride 64 ush
// with XOR swizzle (channel-group p = g ^ (px&7)) -> conflict-free b128 reads.
// WNSPLIT=1: 4 waves tile 2 m-groups x 2 n-groups (LM=8, NTW=4 for 128 co).
// SCALEA: SE applied to staged A (sl[128] from per-block prologue).
// DOMEAN: fused SE pooled-sum. TAILFUSE: dynfilter fused (MFMA e-GEMM).
template <int LM, int NTW, int WNSPLIT, int DOMEAN, int TAILFUSE, int SCALEA>
__global__ __launch_bounds__(256, 2) void conv_mfma(
    const unsigned short* __restrict__ in, const unsigned short* __restrict__ wT,
    const float* __restrict__ bias, unsigned short* __restrict__ out,
    float* __restrict__ meanb, const float* __restrict__ se_mean,
    const float* __restrict__ sw1, const float* __restrict__ sb1,
    const float* __restrict__ sw2, const float* __restrict__ sb2,
    const float* __restrict__ x, const unsigned short* __restrict__ kb,
    float* __restrict__ outf, int Coutp, int Cout, int relu)
{
    __shared__ unsigned short lds[TAILFUSE ? 26624 : 20736];
    __shared__ float slds[136];          // [0:128) sigmoid scales, [128:136) h1
    const int tid = threadIdx.x;
    const int b = blockIdx.y;
    const int row0 = (blockIdx.x >> 3) << 4;
    const int col0 = (blockIdx.x & 7) << 4;
    const int l = tid & 63, wv = tid >> 6;
    const int li = l & 15, lq = l >> 4;
    const int m_base = WNSPLIT ? (wv >> 1) * LM : wv * LM;
    const int n_base = WNSPLIT ? (wv & 1) * NTW : 0;
    const size_t inb = ((size_t)b) << 14;
    const unsigned short* wbase = wT;

    if (SCALEA) {
        if (tid < 8) {
            float s = 0.f;
            for (int j = 0; j < 128; ++j)
                s += sw1[tid * 128 + j] * se_mean[b * 128 + j];
            slds[128 + tid] = fmaxf(s * (1.f / 16384.f) + sb1[tid], 0.f);
        }
        __syncthreads();
        if (tid < 128) {
            float s = sb2[tid];
            #pragma unroll
            for (int j = 0; j < 8; ++j) s += sw2[tid * 8 + j] * slds[128 + j];
            slds[tid] = 1.f / (1.f + expf(-s));
        }
        __syncthreads();
    }

    f32x4 acc[LM][NTW];
    #pragma unroll
    for (int lm = 0; lm < LM; ++lm)
        #pragma unroll
        for (int nt = 0; nt < NTW; ++nt)
            acc[lm][nt] = (f32x4){0.f, 0.f, 0.f, 0.f};

    #pragma unroll 1
    for (int half = 0; half < 2; ++half) {
        float msc[8];
        if (SCALEA) {
            #pragma unroll
            for (int j = 0; j < 8; ++j)
                msc[j] = slds[half * 64 + (tid & 7) * 8 + j];
        }
        __syncthreads();
        for (int u = tid; u < 2592; u += 256) {   // 324 px * 8 ch-groups
            int px = u >> 3, g = u & 7;
            int hr = px / 18, hc = px - hr * 18;
            int gy = row0 - 1 + hr, gx = col0 - 1 + hc;
            bf16x8 v = {0, 0, 0, 0, 0, 0, 0, 0};
            if ((unsigned)gy < 128u && (unsigned)gx < 128u)
                v = *(const bf16x8*)(in + ((inb + (gy << 7) + gx) << 7) + half * 64 + g * 8);
            if (SCALEA) {
                #pragma unroll
                for (int j = 0; j < 8; ++j)
                    v[j] = (short)f2bf(bf2f((unsigned short)v[j]) * msc[j]);
            }
            int p = g ^ (px & 7);                 // XOR swizzle
            *(bf16x8*)(lds + px * 64 + p * 8) = v;
        }
        __syncthreads();

        auto loadB = [&](bf16x8 (&dst)[NTW], int s) {
            int tap = s >> 1, kcl = s & 1;
            const unsigned short* p = wbase +
                (size_t)(tap * 4 + half * 2 + kcl) * (Coutp * 32) +
                (n_base * 16 + li) * 32 + lq * 8;
            #pragma unroll
            for (int nt = 0; nt < NTW; ++nt)
                dst[nt] = *(const bf16x8*)(p + nt * 512);
        };
        auto compute = [&](bf16x8 (&bf)[NTW], int s) {
            int tap = s >> 1, kcl = s & 1;
            int ky = tap / 3, kx = tap - ky * 3;
            int g = kcl * 4 + lq;
            #pragma unroll
            for (int lm = 0; lm < LM; ++lm) {
                int px = (m_base + lm + ky) * 18 + li + kx;
                bf16x8 af = *(const bf16x8*)(lds + px * 64 + ((g ^ (px & 7)) * 8));
                #pragma unroll
                for (int nt = 0; nt < NTW; ++nt)
                    acc[lm][nt] = __builtin_amdgcn_mfma_f32_16x16x32_bf16(
                        af, bf[nt], acc[lm][nt], 0, 0, 0);
            }
        };

        bf16x8 bufA[NTW], bufB[NTW];
        loadB(bufA, 0);
        #pragma unroll 1
        for (int it = 0; it < 18; it += 2) {
            loadB(bufB, it + 1);
            compute(bufA, it);
            if (it + 2 < 18) loadB(bufA, it + 2);
            compute(bufB, it + 1);
        }
    }

    float bv[NTW], msum[NTW];
    #pragma unroll
    for (int nt = 0; nt < NTW; ++nt) {
        int co = (n_base + nt) * 16 + li;
        bv[nt] = (co < Cout) ? bias[co] : 0.f;
        msum[nt] = 0.f;
    }

    if (TAILFUSE) {
        // ---- P (wgt) -> LDS, stride 104 ush; zero pad co 80..95 ----
        __syncthreads();
        #pragma unroll
        for (int lm = 0; lm < LM; ++lm) {
            int rowl = m_base + lm;
            #pragma unroll
            for (int r = 0; r < 4; ++r) {
                int coll = lq * 4 + r;
                #pragma unroll
                for (int nt = 0; nt < NTW; ++nt)
                    lds[(rowl * 16 + coll) * 104 + nt * 16 + li] =
                        f2bf(acc[lm][nt][r] + bv[nt]);
            }
        }
        {
            bf16x8 z = {0, 0, 0, 0, 0, 0, 0, 0};
            *(bf16x8*)(lds + tid * 104 + 80) = z;
            *(bf16x8*)(lds + tid * 104 + 88) = z;
        }
        __syncthreads();

        // ---- e-GEMM: e[px][i] = sum_co P[px][co] * kern[co][i] ----
        f32x4 eacc[4][2];
        #pragma unroll
        for (int mm = 0; mm < 4; ++mm)
            #pragma unroll
            for (int nt = 0; nt < 2; ++nt)
                eacc[mm][nt] = (f32x4){0.f, 0.f, 0.f, 0.f};
        #pragma unroll
        for (int s = 0; s < 3; ++s) {
            bf16x8 kbf[2];
            #pragma unroll
            for (int nt = 0; nt < 2; ++nt)
                kbf[nt] = *(const bf16x8*)(kb + ((s * 2 + nt) * 16 + li) * 32 + lq * 8);
            #pragma unroll
            for (int mm = 0; mm < 4; ++mm) {
                int px = (wv * 4 + mm) * 16 + li;
                bf16x8 pf = *(const bf16x8*)(lds + px * 104 + s * 32 + lq * 8);
                #pragma unroll
                for (int nt = 0; nt < 2; ++nt)
                    eacc[mm][nt] = __builtin_amdgcn_mfma_f32_16x16x32_bf16(
                        pf, kbf[nt], eacc[mm][nt], 0, 0, 0);
            }
        }
        __syncthreads();

        // ---- e (C-layout) -> LDS fp32, stride 33 ----
        float* elds = (float*)lds;
        #pragma unroll
        for (int mm = 0; mm < 4; ++mm) {
            #pragma unroll
            for (int nt = 0; nt < 2; ++nt) {
                int i = nt * 16 + li;
                if (i < 25) {
                    #pragma unroll
                    for (int r = 0; r < 4; ++r) {
                        int px = (wv * 4 + mm) * 16 + lq * 4 + r;
                        elds[px * 33 + i] = eacc[mm][nt][r];
                    }
                }
            }
        }
        __syncthreads();

        // ---- apply ----
        const int h = row0 + (tid >> 4), w = col0 + (tid & 15);
        const int pix = h * 128 + w;
        float e[25];
        #pragma unroll
        for (int i = 0; i < 25; ++i) e[i] = elds[tid * 33 + i];

        int yy[5], xx[5];
        #pragma unroll
        for (int d = 0; d < 5; ++d) {
            int y = h - 2 + d;
            yy[d] = y < 0 ? -y : (y > 127 ? 254 - y : y);
            int xv = w - 2 + d;
            xx[d] = xv < 0 ? -xv : (xv > 127 ? 254 - xv : xv);
        }
        #pragma unroll
        for (int c = 0; c < 3; ++c) {
            const float* xc = x + ((size_t)(b * 3 + c) << 14);
            float s = 0.f;
            #pragma unroll
            for (int dy = 0; dy < 5; ++dy)
                #pragma unroll
                for (int dx = 0; dx < 5; ++dx)
                    s += e[dy * 5 + dx] * xc[yy[dy] * 128 + xx[dx]];
            outf[((size_t)(b * 3 + c) << 14) + pix] = s;
        }
        return;
    }

    #pragma unroll
    for (int lm = 0; lm < LM; ++lm) {
        int row = row0 + m_base + lm;
        #pragma unroll
        for (int r = 0; r < 4; ++r) {
            int col = col0 + lq * 4 + r;
            size_t pbase = (inb + row * 128 + col) * (size_t)Coutp;
            #pragma unroll
            for (int nt = 0; nt < NTW; ++nt) {
                float v = acc[lm][nt][r] + bv[nt];
                if (relu) v = fmaxf(v, 0.f);
                if (DOMEAN) msum[nt] += v;
                out[pbase + (n_base + nt) * 16 + li] = f2bf(v);
            }
        }
    }
    if (DOMEAN) {
        #pragma unroll
        for (int nt = 0; nt < NTW; ++nt) {
            float t = msum[nt];
            t += __shfl_xor(t, 16, 64);
            t += __shfl_xor(t, 32, 64);
            if (lq == 0)
                atomicAdd(&meanb[b * 128 + (n_base + nt) * 16 + li], t);
        }
    }
}

// ---------------------------------------------------------------------------
extern "C" void kernel_launch(void* const* d_in, const int* in_sizes, int n_in,
                              void* d_out, int out_size, void* d_ws, size_t ws_size,
                              hipStream_t stream)
{
    const float* x      = (const float*)d_in[0];
    const float* w_head = (const float*)d_in[1];
    const float* b_head = (const float*)d_in[2];
    const float* w_h1a  = (const float*)d_in[3];
    const float* b_h1a  = (const float*)d_in[4];
    const float* w_h1b  = (const float*)d_in[5];
    const float* b_h1b  = (const float*)d_in[6];
    const float* du1_w1 = (const float*)d_in[7];
    const float* du1_b1 = (const float*)d_in[8];
    const float* du1_w2 = (const float*)d_in[9];
    const float* du1_b2 = (const float*)d_in[10];
    const float* w_h2a  = (const float*)d_in[11];
    const float* b_h2a  = (const float*)d_in[12];
    const float* w_h2b  = (const float*)d_in[13];
    const float* b_h2b  = (const float*)d_in[14];
    const float* du2_w1 = (const float*)d_in[15];
    const float* du2_b1 = (const float*)d_in[16];
    const float* du2_w2 = (const float*)d_in[17];
    const float* du2_b2 = (const float*)d_in[18];
    const float* w_tail = (const float*)d_in[19];
    const float* b_tail = (const float*)d_in[20];
    const float* kern   = (const float*)d_in[21];
    float* out = (float*)d_out;

    unsigned short* fb0  = (unsigned short*)d_ws;        // 16,777,216 elems
    unsigned short* fb1  = fb0 + 16777216;
    unsigned short* wt1  = fb1 + 16777216;               // 147456 each
    unsigned short* wt2  = wt1 + 147456;
    unsigned short* wt3  = wt2 + 147456;
    unsigned short* wt4  = wt3 + 147456;
    unsigned short* wtt  = wt4 + 147456;                 // 92160
    unsigned short* kbb  = wtt + 92160;                  // 3072 (kern B-frag)
    float* mean1  = (float*)(kbb + 3072);                // 1024
    float* mean2  = mean1 + 1024;

    dim3 blk(256);
    // prep: head conv (2048 blocks) + all weight transforms + mean zeroing
    prep<<<dim3(5504), blk, 0, stream>>>(x, w_head, b_head, fb0,
                                         w_h1a, w_h1b, w_h2a, w_h2b, w_tail,
                                         kern, wt1, wt2, wt3, wt4, wtt, kbb,
                                         mean1);

    dim3 cgrid(64, 8);   // 512 blocks: 64 tiles/batch x 8 batches
    conv_mfma<8, 4, 1, 0, 0, 0><<<cgrid, blk, 0, stream>>>(
        fb0, wt1, b_h1a, fb1, nullptr, nullptr, nullptr, nullptr, nullptr,
        nullptr, nullptr, nullptr, nullptr, 128, 128, 1);
    conv_mfma<8, 4, 1, 1, 0, 0><<<cgrid, blk, 0, stream>>>(
        fb1, wt2, b_h1b, fb0, mean1, nullptr, nullptr, nullptr, nullptr,
        nullptr, nullptr, nullptr, nullptr, 128, 128, 1);

    // h2a: SE1 scale applied to staged A (reads mean1 + du1 params)
    conv_mfma<8, 4, 1, 0, 0, 1><<<cgrid, blk, 0, stream>>>(
        fb0, wt3, b_h2a, fb1, nullptr, mean1, du1_w1, du1_b1, du1_w2, du1_b2,
        nullptr, nullptr, nullptr, 128, 128, 1);
    conv_mfma<8, 4, 1, 1, 0, 0><<<cgrid, blk, 0, stream>>>(
        fb1, wt4, b_h2b, fb0, mean2, nullptr, nullptr, nullptr, nullptr,
        nullptr, nullptr, nullptr, nullptr, 128, 128, 1);

    // tail conv (SE2 scale on staged A) + fused dynamic filter e-GEMM
    conv_mfma<4, 5, 0, 0, 1, 1><<<cgrid, blk, 0, stream>>>(
        fb0, wtt, b_tail, nullptr, nullptr, mean2, du2_w1, du2_b1, du2_w2,
        du2_b2, x, kbb, out, 80, 72, 0);
}

// Round 8
// 325.223 us; speedup vs baseline: 1.1353x; 1.0200x over previous
//
#include <hip/hip_runtime.h>
#include <math.h>

// ---------------------------------------------------------------------------
// R22: de-couple codegen. R21 won overall (331.7, best) but ALL convs went
// 46.7->51.5us -- including SCALEA=0 paths whose source should be R14-equal.
// Suspect rule #19 (template-variant codegen coupling: slds decl + extra args
// perturbed the tuned schedule). Fix: conv_mfma restored BYTE-EXACT to R14
// (own signature incl wstride, no slds, LDS 41472) for conv1/2/4; SCALEA and
// TAILFUSE live in a SEPARATE template conv_mfma_se (R21 body) for h2a+tail.
// Aux wins kept: no wscale8f, merged prep, 6 dispatches.
// ---------------------------------------------------------------------------

typedef __attribute__((ext_vector_type(8))) short bf16x8;
typedef __attribute__((ext_vector_type(4))) float f32x4;

__device__ inline float bf2f(unsigned short u) {
    unsigned v = ((unsigned)u) << 16;
    return __builtin_bit_cast(float, v);
}
__device__ inline unsigned short f2bf(float f) {
    unsigned u = __builtin_bit_cast(unsigned, f);
    u += 0x7FFF + ((u >> 16) & 1);   // RNE
    return (unsigned short)(u >> 16);
}

// ---- weight transform helper: [Co][128][3][3] f32 -> [tap*4+kc][Coutp][32] -
__device__ inline void wtrans_one(const float* w, unsigned short* wT,
                                  int Co, int Coutp, int idx)
{
    int ch = idx & 31;
    int rest = idx >> 5;
    int co = rest % Coutp;
    int slice = rest / Coutp;
    int kc = slice & 3, tap = slice >> 2;
    float v = (co < Co) ? w[((size_t)(co * 128 + kc * 32 + ch)) * 9 + tap] : 0.f;
    wT[idx] = f2bf(v);
}

// ---------------- prep: head conv (bid<2048) + weight transforms ------------
__global__ __launch_bounds__(256) void prep(
    const float* __restrict__ x, const float* __restrict__ wh,
    const float* __restrict__ bh, unsigned short* __restrict__ fb0,
    const float* __restrict__ w0, const float* __restrict__ w1,
    const float* __restrict__ w2, const float* __restrict__ w3,
    const float* __restrict__ w4, const float* __restrict__ kern,
    unsigned short* __restrict__ t0, unsigned short* __restrict__ t1,
    unsigned short* __restrict__ t2, unsigned short* __restrict__ t3,
    unsigned short* __restrict__ t4, unsigned short* __restrict__ kb,
    float* __restrict__ meanz)
{
    __shared__ float wlds[216];          // [ci][tap][co8]
    __shared__ float tile[3][34 * 34];
    const int tid = threadIdx.x;
    const int bid = blockIdx.x;

    if (bid >= 2048) {                   // ---- weight-transform blocks ----
        int r = bid - 2048;              // 0..3455
        int y = r / 576;
        int idx = (r - y * 576) * 256 + tid;
        if (y < 4) {
            const float* w = y == 0 ? w0 : y == 1 ? w1 : y == 2 ? w2 : w3;
            unsigned short* t = y == 0 ? t0 : y == 1 ? t1 : y == 2 ? t2 : t3;
            wtrans_one(w, t, 128, 128, idx);
        } else if (y == 4) {
            if (idx < 9 * 4 * 80 * 32) wtrans_one(w4, t4, 72, 80, idx);
        } else {
            if (idx < 3072) {
                int lq = (idx & 31) >> 3, j = idx & 7;
                int row = idx >> 5;
                int li = row & 15, snt = row >> 4;
                int s = snt >> 1, nt = snt & 1;
                int co = s * 32 + lq * 8 + j, i = nt * 16 + li;
                float v = (co < 72 && i < 25) ? kern[co * 25 + i] : 0.f;
                kb[idx] = f2bf(v);
            }
            if (idx < 2048) meanz[idx] = 0.f;   // zero mean1+mean2
        }
        return;
    }

    // ---- head conv: bid = bx + 16*cog + 256*b ----
    const int bx = bid & 15, cog = (bid >> 4) & 15, b = bid >> 8;
    const int tile_y = (bx >> 2) * 32, tile_x = (bx & 3) * 32;

    if (tid < 216) {
        int co = tid & 7, rest = tid >> 3, tap = rest % 9, ci = rest / 9;
        wlds[tid] = wh[((cog * 8 + co) * 3 + ci) * 9 + tap];
    }
    for (int idx = tid; idx < 3 * 34 * 34; idx += 256) {
        int ci = idx / 1156, rem = idx - ci * 1156;
        int rr = rem / 34, c = rem - rr * 34;
        int gy = tile_y - 1 + rr, gx = tile_x - 1 + c;
        float v = 0.f;
        if ((unsigned)gy < 128u && (unsigned)gx < 128u)
            v = x[(((size_t)(b * 3 + ci)) << 14) + (gy << 7) + gx];
        tile[ci][rem] = v;
    }
    __syncthreads();

    const int ty = tid >> 4, tx = tid & 15, py = ty * 2;
    float acc[2][2][8];
    #pragma unroll
    for (int r = 0; r < 2; ++r)
        #pragma unroll
        for (int h = 0; h < 2; ++h)
            #pragma unroll
            for (int co = 0; co < 8; ++co) acc[r][h][co] = 0.f;

    #pragma unroll
    for (int ci = 0; ci < 3; ++ci) {
        #pragma unroll
        for (int ky = 0; ky < 3; ++ky) {
            #pragma unroll
            for (int kx = 0; kx < 3; ++kx) {
                const float* wp = wlds + (ci * 9 + ky * 3 + kx) * 8;
                float i00 = tile[ci][(py + ky) * 34 + tx + kx];
                float i01 = tile[ci][(py + ky) * 34 + tx + 16 + kx];
                float i10 = tile[ci][(py + 1 + ky) * 34 + tx + kx];
                float i11 = tile[ci][(py + 1 + ky) * 34 + tx + 16 + kx];
                #pragma unroll
                for (int co = 0; co < 8; ++co) {
                    float wv = wp[co];
                    acc[0][0][co] += i00 * wv;
                    acc[0][1][co] += i01 * wv;
                    acc[1][0][co] += i10 * wv;
                    acc[1][1][co] += i11 * wv;
                }
            }
        }
    }

    #pragma unroll
    for (int r = 0; r < 2; ++r) {
        #pragma unroll
        for (int h = 0; h < 2; ++h) {
            int gy = tile_y + py + r, gx = tile_x + tx + h * 16;
            bf16x8 pv;
            #pragma unroll
            for (int co = 0; co < 8; ++co)
                pv[co] = (short)f2bf(acc[r][h][co] + bh[cog * 8 + co]);
            *(bf16x8*)(fb0 + (((((size_t)b << 14) + gy * 128 + gx)) << 7) + cog * 8) = pv;
        }
    }
}

// ---------------- main conv: implicit GEMM, bf16 MFMA (R14 EXACT) -----------
// Block: 16x16 px tile; A staged in two 64-ch halves, UNPADDED stride 64 ush
// with XOR swizzle (channel-group p = g ^ (px&7)) -> conflict-free b128 reads.
// WNSPLIT=1: 4 waves tile 2 m-groups x 2 n-groups (LM=8, NTW=4 for 128 co).
template <int LM, int NTW, int WNSPLIT, int DOMEAN>
__global__ __launch_bounds__(256, 2) void conv_mfma(
    const unsigned short* __restrict__ in, const unsigned short* __restrict__ wT,
    size_t wstride, const float* __restrict__ bias, unsigned short* __restrict__ out,
    float* __restrict__ meanb, const float* __restrict__ x,
    const unsigned short* __restrict__ kb, float* __restrict__ outf,
    int Coutp, int Cout, int relu)
{
    __shared__ unsigned short lds[20736];
    const int tid = threadIdx.x;
    const int b = blockIdx.y;
    const int row0 = (blockIdx.x >> 3) << 4;
    const int col0 = (blockIdx.x & 7) << 4;
    const int l = tid & 63, wv = tid >> 6;
    const int li = l & 15, lq = l >> 4;
    const int m_base = WNSPLIT ? (wv >> 1) * LM : wv * LM;
    const int n_base = WNSPLIT ? (wv & 1) * NTW : 0;
    const size_t inb = ((size_t)b) << 14;
    const unsigned short* wbase = wT + (size_t)b * wstride;

    f32x4 acc[LM][NTW];
    #pragma unroll
    for (int lm = 0; lm < LM; ++lm)
        #pragma unroll
        for (int nt = 0; nt < NTW; ++nt)
            acc[lm][nt] = (f32x4){0.f, 0.f, 0.f, 0.f};

    #pragma unroll 1
    for (int half = 0; half < 2; ++half) {
        __syncthreads();
        for (int u = tid; u < 2592; u += 256) {   // 324 px * 8 ch-groups
            int px = u >> 3, g = u & 7;
            int hr = px / 18, hc = px - hr * 18;
            int gy = row0 - 1 + hr, gx = col0 - 1 + hc;
            bf16x8 v = {0, 0, 0, 0, 0, 0, 0, 0};
            if ((unsigned)gy < 128u && (unsigned)gx < 128u)
                v = *(const bf16x8*)(in + ((inb + (gy << 7) + gx) << 7) + half * 64 + g * 8);
            int p = g ^ (px & 7);                 // XOR swizzle
            *(bf16x8*)(lds + px * 64 + p * 8) = v;
        }
        __syncthreads();

        auto loadB = [&](bf16x8 (&dst)[NTW], int s) {
            int tap = s >> 1, kcl = s & 1;
            const unsigned short* p = wbase +
                (size_t)(tap * 4 + half * 2 + kcl) * (Coutp * 32) +
                (n_base * 16 + li) * 32 + lq * 8;
            #pragma unroll
            for (int nt = 0; nt < NTW; ++nt)
                dst[nt] = *(const bf16x8*)(p + nt * 512);
        };
        auto compute = [&](bf16x8 (&bf)[NTW], int s) {
            int tap = s >> 1, kcl = s & 1;
            int ky = tap / 3, kx = tap - ky * 3;
            int g = kcl * 4 + lq;
            #pragma unroll
            for (int lm = 0; lm < LM; ++lm) {
                int px = (m_base + lm + ky) * 18 + li + kx;
                bf16x8 af = *(const bf16x8*)(lds + px * 64 + ((g ^ (px & 7)) * 8));
                #pragma unroll
                for (int nt = 0; nt < NTW; ++nt)
                    acc[lm][nt] = __builtin_amdgcn_mfma_f32_16x16x32_bf16(
                        af, bf[nt], acc[lm][nt], 0, 0, 0);
            }
        };

        bf16x8 bufA[NTW], bufB[NTW];
        loadB(bufA, 0);
        #pragma unroll 1
        for (int it = 0; it < 18; it += 2) {
            loadB(bufB, it + 1);
            compute(bufA, it);
            if (it + 2 < 18) loadB(bufA, it + 2);
            compute(bufB, it + 1);
        }
    }

    float bv[NTW], msum[NTW];
    #pragma unroll
    for (int nt = 0; nt < NTW; ++nt) {
        int co = (n_base + nt) * 16 + li;
        bv[nt] = (co < Cout) ? bias[co] : 0.f;
        msum[nt] = 0.f;
    }

    #pragma unroll
    for (int lm = 0; lm < LM; ++lm) {
        int row = row0 + m_base + lm;
        #pragma unroll
        for (int r = 0; r < 4; ++r) {
            int col = col0 + lq * 4 + r;
            size_t pbase = (inb + row * 128 + col) * (size_t)Coutp;
            #pragma unroll
            for (int nt = 0; nt < NTW; ++nt) {
                float v = acc[lm][nt][r] + bv[nt];
                if (relu) v = fmaxf(v, 0.f);
                if (DOMEAN) msum[nt] += v;
                out[pbase + (n_base + nt) * 16 + li] = f2bf(v);
            }
        }
    }
    if (DOMEAN) {
        #pragma unroll
        for (int nt = 0; nt < NTW; ++nt) {
            float t = msum[nt];
            t += __shfl_xor(t, 16, 64);
            t += __shfl_xor(t, 32, 64);
            if (lq == 0)
                atomicAdd(&meanb[b * 128 + (n_base + nt) * 16 + li], t);
        }
    }
}

// ---------------- SE-scaled conv (separate function: codegen decoupled) -----
// SCALEA hardwired: sl[128] per-block prologue, applied during A staging.
// TAILFUSE: dynamic-filter fusion (MFMA e-GEMM) writing final output.
template <int LM, int NTW, int WNSPLIT, int DOMEAN, int TAILFUSE>
__global__ __launch_bounds__(256, 2) void conv_mfma_se(
    const unsigned short* __restrict__ in, const unsigned short* __restrict__ wT,
    const float* __restrict__ bias, unsigned short* __restrict__ out,
    float* __restrict__ meanb, const float* __restrict__ se_mean,
    const float* __restrict__ sw1, const float* __restrict__ sb1,
    const float* __restrict__ sw2, const float* __restrict__ sb2,
    const float* __restrict__ x, const unsigned short* __restrict__ kb,
    float* __restrict__ outf, int Coutp, int Cout, int relu)
{
    __shared__ unsigned short lds[TAILFUSE ? 26624 : 20736];
    __shared__ float slds[136];          // [0:128) sigmoid scales, [128:136) h1
    const int tid = threadIdx.x;
    const int b = blockIdx.y;
    const int row0 = (blockIdx.x >> 3) << 4;
    const int col0 = (blockIdx.x & 7) << 4;
    const int l = tid & 63, wv = tid >> 6;
    const int li = l & 15, lq = l >> 4;
    const int m_base = WNSPLIT ? (wv >> 1) * LM : wv * LM;
    const int n_base = WNSPLIT ? (wv & 1) * NTW : 0;
    const size_t inb = ((size_t)b) << 14;
    const unsigned short* wbase = wT;

    if (tid < 8) {
        float s = 0.f;
        for (int j = 0; j < 128; ++j)
            s += sw1[tid * 128 + j] * se_mean[b * 128 + j];
        slds[128 + tid] = fmaxf(s * (1.f / 16384.f) + sb1[tid], 0.f);
    }
    __syncthreads();
    if (tid < 128) {
        float s = sb2[tid];
        #pragma unroll
        for (int j = 0; j < 8; ++j) s += sw2[tid * 8 + j] * slds[128 + j];
        slds[tid] = 1.f / (1.f + expf(-s));
    }
    __syncthreads();

    f32x4 acc[LM][NTW];
    #pragma unroll
    for (int lm = 0; lm < LM; ++lm)
        #pragma unroll
        for (int nt = 0; nt < NTW; ++nt)
            acc[lm][nt] = (f32x4){0.f, 0.f, 0.f, 0.f};

    #pragma unroll 1
    for (int half = 0; half < 2; ++half) {
        float msc[8];
        #pragma unroll
        for (int j = 0; j < 8; ++j)
            msc[j] = slds[half * 64 + (tid & 7) * 8 + j];
        __syncthreads();
        for (int u = tid; u < 2592; u += 256) {   // 324 px * 8 ch-groups
            int px = u >> 3, g = u & 7;
            int hr = px / 18, hc = px - hr * 18;
            int gy = row0 - 1 + hr, gx = col0 - 1 + hc;
            bf16x8 v = {0, 0, 0, 0, 0, 0, 0, 0};
            if ((unsigned)gy < 128u && (unsigned)gx < 128u)
                v = *(const bf16x8*)(in + ((inb + (gy << 7) + gx) << 7) + half * 64 + g * 8);
            #pragma unroll
            for (int j = 0; j < 8; ++j)
                v[j] = (short)f2bf(bf2f((unsigned short)v[j]) * msc[j]);
            int p = g ^ (px & 7);                 // XOR swizzle
            *(bf16x8*)(lds + px * 64 + p * 8) = v;
        }
        __syncthreads();

        auto loadB = [&](bf16x8 (&dst)[NTW], int s) {
            int tap = s >> 1, kcl = s & 1;
            const unsigned short* p = wbase +
                (size_t)(tap * 4 + half * 2 + kcl) * (Coutp * 32) +
                (n_base * 16 + li) * 32 + lq * 8;
            #pragma unroll
            for (int nt = 0; nt < NTW; ++nt)
                dst[nt] = *(const bf16x8*)(p + nt * 512);
        };
        auto compute = [&](bf16x8 (&bf)[NTW], int s) {
            int tap = s >> 1, kcl = s & 1;
            int ky = tap / 3, kx = tap - ky * 3;
            int g = kcl * 4 + lq;
            #pragma unroll
            for (int lm = 0; lm < LM; ++lm) {
                int px = (m_base + lm + ky) * 18 + li + kx;
                bf16x8 af = *(const bf16x8*)(lds + px * 64 + ((g ^ (px & 7)) * 8));
                #pragma unroll
                for (int nt = 0; nt < NTW; ++nt)
                    acc[lm][nt] = __builtin_amdgcn_mfma_f32_16x16x32_bf16(
                        af, bf[nt], acc[lm][nt], 0, 0, 0);
            }
        };

        bf16x8 bufA[NTW], bufB[NTW];
        loadB(bufA, 0);
        #pragma unroll 1
        for (int it = 0; it < 18; it += 2) {
            loadB(bufB, it + 1);
            compute(bufA, it);
            if (it + 2 < 18) loadB(bufA, it + 2);
            compute(bufB, it + 1);
        }
    }

    float bv[NTW], msum[NTW];
    #pragma unroll
    for (int nt = 0; nt < NTW; ++nt) {
        int co = (n_base + nt) * 16 + li;
        bv[nt] = (co < Cout) ? bias[co] : 0.f;
        msum[nt] = 0.f;
    }

    if (TAILFUSE) {
        // ---- P (wgt) -> LDS, stride 104 ush; zero pad co 80..95 ----
        __syncthreads();
        #pragma unroll
        for (int lm = 0; lm < LM; ++lm) {
            int rowl = m_base + lm;
            #pragma unroll
            for (int r = 0; r < 4; ++r) {
                int coll = lq * 4 + r;
                #pragma unroll
                for (int nt = 0; nt < NTW; ++nt)
                    lds[(rowl * 16 + coll) * 104 + nt * 16 + li] =
                        f2bf(acc[lm][nt][r] + bv[nt]);
            }
        }
        {
            bf16x8 z = {0, 0, 0, 0, 0, 0, 0, 0};
            *(bf16x8*)(lds + tid * 104 + 80) = z;
            *(bf16x8*)(lds + tid * 104 + 88) = z;
        }
        __syncthreads();

        // ---- e-GEMM: e[px][i] = sum_co P[px][co] * kern[co][i] ----
        f32x4 eacc[4][2];
        #pragma unroll
        for (int mm = 0; mm < 4; ++mm)
            #pragma unroll
            for (int nt = 0; nt < 2; ++nt)
                eacc[mm][nt] = (f32x4){0.f, 0.f, 0.f, 0.f};
        #pragma unroll
        for (int s = 0; s < 3; ++s) {
            bf16x8 kbf[2];
            #pragma unroll
            for (int nt = 0; nt < 2; ++nt)
                kbf[nt] = *(const bf16x8*)(kb + ((s * 2 + nt) * 16 + li) * 32 + lq * 8);
            #pragma unroll
            for (int mm = 0; mm < 4; ++mm) {
                int px = (wv * 4 + mm) * 16 + li;
                bf16x8 pf = *(const bf16x8*)(lds + px * 104 + s * 32 + lq * 8);
                #pragma unroll
                for (int nt = 0; nt < 2; ++nt)
                    eacc[mm][nt] = __builtin_amdgcn_mfma_f32_16x16x32_bf16(
                        pf, kbf[nt], eacc[mm][nt], 0, 0, 0);
            }
        }
        __syncthreads();

        // ---- e (C-layout) -> LDS fp32, stride 33 ----
        float* elds = (float*)lds;
        #pragma unroll
        for (int mm = 0; mm < 4; ++mm) {
            #pragma unroll
            for (int nt = 0; nt < 2; ++nt) {
                int i = nt * 16 + li;
                if (i < 25) {
                    #pragma unroll
                    for (int r = 0; r < 4; ++r) {
                        int px = (wv * 4 + mm) * 16 + lq * 4 + r;
                        elds[px * 33 + i] = eacc[mm][nt][r];
                    }
                }
            }
        }
        __syncthreads();

        // ---- apply ----
        const int h = row0 + (tid >> 4), w = col0 + (tid & 15);
        const int pix = h * 128 + w;
        float e[25];
        #pragma unroll
        for (int i = 0; i < 25; ++i) e[i] = elds[tid * 33 + i];

        int yy[5], xx[5];
        #pragma unroll
        for (int d = 0; d < 5; ++d) {
            int y = h - 2 + d;
            yy[d] = y < 0 ? -y : (y > 127 ? 254 - y : y);
            int xv = w - 2 + d;
            xx[d] = xv < 0 ? -xv : (xv > 127 ? 254 - xv : xv);
        }
        #pragma unroll
        for (int c = 0; c < 3; ++c) {
            const float* xc = x + ((size_t)(b * 3 + c) << 14);
            float s = 0.f;
            #pragma unroll
            for (int dy = 0; dy < 5; ++dy)
                #pragma unroll
                for (int dx = 0; dx < 5; ++dx)
                    s += e[dy * 5 + dx] * xc[yy[dy] * 128 + xx[dx]];
            outf[((size_t)(b * 3 + c) << 14) + pix] = s;
        }
        return;
    }

    #pragma unroll
    for (int lm = 0; lm < LM; ++lm) {
        int row = row0 + m_base + lm;
        #pragma unroll
        for (int r = 0; r < 4; ++r) {
            int col = col0 + lq * 4 + r;
            size_t pbase = (inb + row * 128 + col) * (size_t)Coutp;
            #pragma unroll
            for (int nt = 0; nt < NTW; ++nt) {
                float v = acc[lm][nt][r] + bv[nt];
                if (relu) v = fmaxf(v, 0.f);
                if (DOMEAN) msum[nt] += v;
                out[pbase + (n_base + nt) * 16 + li] = f2bf(v);
            }
        }
    }
    if (DOMEAN) {
        #pragma unroll
        for (int nt = 0; nt < NTW; ++nt) {
            float t = msum[nt];
            t += __shfl_xor(t, 16, 64);
            t += __shfl_xor(t, 32, 64);
            if (lq == 0)
                atomicAdd(&meanb[b * 128 + (n_base + nt) * 16 + li], t);
        }
    }
}

// ---------------------------------------------------------------------------
extern "C" void kernel_launch(void* const* d_in, const int* in_sizes, int n_in,
                              void* d_out, int out_size, void* d_ws, size_t ws_size,
                              hipStream_t stream)
{
    const float* x      = (const float*)d_in[0];
    const float* w_head = (const float*)d_in[1];
    const float* b_head = (const float*)d_in[2];
    const float* w_h1a  = (const float*)d_in[3];
    const float* b_h1a  = (const float*)d_in[4];
    const float* w_h1b  = (const float*)d_in[5];
    const float* b_h1b  = (const float*)d_in[6];
    const float* du1_w1 = (const float*)d_in[7];
    const float* du1_b1 = (const float*)d_in[8];
    const float* du1_w2 = (const float*)d_in[9];
    const float* du1_b2 = (const float*)d_in[10];
    const float* w_h2a  = (const float*)d_in[11];
    const float* b_h2a  = (const float*)d_in[12];
    const float* w_h2b  = (const float*)d_in[13];
    const float* b_h2b  = (const float*)d_in[14];
    const float* du2_w1 = (const float*)d_in[15];
    const float* du2_b1 = (const float*)d_in[16];
    const float* du2_w2 = (const float*)d_in[17];
    const float* du2_b2 = (const float*)d_in[18];
    const float* w_tail = (const float*)d_in[19];
    const float* b_tail = (const float*)d_in[20];
    const float* kern   = (const float*)d_in[21];
    float* out = (float*)d_out;

    unsigned short* fb0  = (unsigned short*)d_ws;        // 16,777,216 elems
    unsigned short* fb1  = fb0 + 16777216;
    unsigned short* wt1  = fb1 + 16777216;               // 147456 each
    unsigned short* wt2  = wt1 + 147456;
    unsigned short* wt3  = wt2 + 147456;
    unsigned short* wt4  = wt3 + 147456;
    unsigned short* wtt  = wt4 + 147456;                 // 92160
    unsigned short* kbb  = wtt + 92160;                  // 3072 (kern B-frag)
    float* mean1  = (float*)(kbb + 3072);                // 1024
    float* mean2  = mean1 + 1024;

    dim3 blk(256);
    // prep: head conv (2048 blocks) + all weight transforms + mean zeroing
    prep<<<dim3(5504), blk, 0, stream>>>(x, w_head, b_head, fb0,
                                         w_h1a, w_h1b, w_h2a, w_h2b, w_tail,
                                         kern, wt1, wt2, wt3, wt4, wtt, kbb,
                                         mean1);

    dim3 cgrid(64, 8);   // 512 blocks: 64 tiles/batch x 8 batches
    conv_mfma<8, 4, 1, 0><<<cgrid, blk, 0, stream>>>(
        fb0, wt1, 0, b_h1a, fb1, nullptr, nullptr, nullptr, nullptr, 128, 128, 1);
    conv_mfma<8, 4, 1, 1><<<cgrid, blk, 0, stream>>>(
        fb1, wt2, 0, b_h1b, fb0, mean1, nullptr, nullptr, nullptr, 128, 128, 1);

    // h2a: SE1 scale applied to staged A (reads mean1 + du1 params)
    conv_mfma_se<8, 4, 1, 0, 0><<<cgrid, blk, 0, stream>>>(
        fb0, wt3, b_h2a, fb1, nullptr, mean1, du1_w1, du1_b1, du1_w2, du1_b2,
        nullptr, nullptr, nullptr, 128, 128, 1);
    conv_mfma<8, 4, 1, 1><<<cgrid, blk, 0, stream>>>(
        fb1, wt4, 0, b_h2b, fb0, mean2, nullptr, nullptr, nullptr, 128, 128, 1);

    // tail conv (SE2 scale on staged A) + fused dynamic filter e-GEMM
    conv_mfma_se<4, 5, 0, 0, 1><<<cgrid, blk, 0, stream>>>(
        fb0, wtt, b_tail, nullptr, nullptr, mean2, du2_w1, du2_b1, du2_w2,
        du2_b2, x, kbb, out, 80, 72, 0);
}

// Round 9
// 318.831 us; speedup vs baseline: 1.1580x; 1.0200x over previous
//
#include <hip/hip_runtime.h>
#include <math.h>

// ---------------------------------------------------------------------------
// R23 = R22 + two isolated aux cuts (conv_mfma template UNTOUCHED - 5-for-5
// fragility lesson):
//  (1) conv_mfma_se prologue wave-parallelized: 8 groups x 32 lanes, float4
//      loads + shfl_xor reduce (~300cy) replaces the serial tid<8 128-iter
//      dot (~3-4k cy with 248 idle lanes). ~2-3us per SE conv.
//  (2) prep weight-transform rewritten: block stages contiguous 8-co chunk
//      (36KB) of w via float4 into LDS (coalesced), writes transposed slices
//      (512B contiguous per (tap,kc); stride-9 LDS reads conflict-free since
//      gcd(9,32)=1). wtrans blocks 3456 -> 75; kills the 36B-strided 4B loads.
// ---------------------------------------------------------------------------

typedef __attribute__((ext_vector_type(8))) short bf16x8;
typedef __attribute__((ext_vector_type(4))) float f32x4;

__device__ inline float bf2f(unsigned short u) {
    unsigned v = ((unsigned)u) << 16;
    return __builtin_bit_cast(float, v);
}
__device__ inline unsigned short f2bf(float f) {
    unsigned u = __builtin_bit_cast(unsigned, f);
    u += 0x7FFF + ((u >> 16) & 1);   // RNE
    return (unsigned short)(u >> 16);
}

// ---------------- prep: head conv (bid<2048) + weight transforms ------------
// bid < 2048          : head conv (bx = bid&15, cog = (bid>>4)&15, b = bid>>8)
// bid in [2048,2112)  : wt1..4 transpose, m = (bid-2048)>>4, co0 = ((bid-2048)&15)*8
// bid in [2112,2122)  : wtt transpose, co0 = (bid-2112)*8 (Co=72, zeros beyond)
// bid == 2122         : kb build + mean zeroing
__global__ __launch_bounds__(256) void prep(
    const float* __restrict__ x, const float* __restrict__ wh,
    const float* __restrict__ bh, unsigned short* __restrict__ fb0,
    const float* __restrict__ w0, const float* __restrict__ w1,
    const float* __restrict__ w2, const float* __restrict__ w3,
    const float* __restrict__ w4, const float* __restrict__ kern,
    unsigned short* __restrict__ t0, unsigned short* __restrict__ t1,
    unsigned short* __restrict__ t2, unsigned short* __restrict__ t3,
    unsigned short* __restrict__ t4, unsigned short* __restrict__ kb,
    float* __restrict__ meanz)
{
    __shared__ float scratch[9216];      // 36 KB: wtrans chunk / head tile+wlds
    const int tid = threadIdx.x;
    const int bid = blockIdx.x;

    if (bid >= 2048) {
        if (bid == 2122) {               // ---- kb + mean zeroing ----
            for (int idx = tid; idx < 3072; idx += 256) {
                int lq = (idx & 31) >> 3, j = idx & 7;
                int row = idx >> 5;
                int li = row & 15, snt = row >> 4;
                int s = snt >> 1, nt = snt & 1;
                int co = s * 32 + lq * 8 + j, i = nt * 16 + li;
                float v = (co < 72 && i < 25) ? kern[co * 25 + i] : 0.f;
                kb[idx] = f2bf(v);
            }
            for (int idx = tid; idx < 2048; idx += 256) meanz[idx] = 0.f;
            return;
        }
        // ---- coalesced weight transpose, 8-co chunk per block ----
        const float* w;
        unsigned short* t;
        int Coutp, Co, co0;
        if (bid < 2112) {
            int r = bid - 2048;
            int m = r >> 4;
            co0 = (r & 15) * 8;
            w = m == 0 ? w0 : m == 1 ? w1 : m == 2 ? w2 : w3;
            t = m == 0 ? t0 : m == 1 ? t1 : m == 2 ? t2 : t3;
            Coutp = 128; Co = 128;
        } else {
            co0 = (bid - 2112) * 8;
            w = w4; t = t4; Coutp = 80; Co = 72;
        }
        // stage w[co0..co0+8)[128ch][9taps] = 9216 floats, contiguous
        const float4* src = (const float4*)(w + (size_t)co0 * 1152);
        for (int i = tid; i < 2304; i += 256) {
            float4 v = {0.f, 0.f, 0.f, 0.f};
            int co_off = (i * 4) / 1152;
            if (co0 + co_off < Co) v = src[i];
            ((float4*)scratch)[i] = v;
        }
        __syncthreads();
        // write transposed: out[((tap*4+kc)*Coutp + co0+co)*32 + ch32]
        const int co = (tid >> 5) & 7, ch32 = tid & 31;
        #pragma unroll
        for (int tap = 0; tap < 9; ++tap)
            #pragma unroll
            for (int kc = 0; kc < 4; ++kc)
                t[((size_t)(tap * 4 + kc) * Coutp + co0 + co) * 32 + ch32] =
                    f2bf(scratch[(co * 128 + kc * 32 + ch32) * 9 + tap]);
        return;
    }

    // ---- head conv ----
    float* wlds = scratch;               // 216
    float* tile = scratch + 216;         // 3 * 1156
    const int bx = bid & 15, cog = (bid >> 4) & 15, b = bid >> 8;
    const int tile_y = (bx >> 2) * 32, tile_x = (bx & 3) * 32;

    if (tid < 216) {
        int co = tid & 7, rest = tid >> 3, tap = rest % 9, ci = rest / 9;
        wlds[tid] = wh[((cog * 8 + co) * 3 + ci) * 9 + tap];
    }
    for (int idx = tid; idx < 3 * 34 * 34; idx += 256) {
        int ci = idx / 1156, rem = idx - ci * 1156;
        int rr = rem / 34, c = rem - rr * 34;
        int gy = tile_y - 1 + rr, gx = tile_x - 1 + c;
        float v = 0.f;
        if ((unsigned)gy < 128u && (unsigned)gx < 128u)
            v = x[(((size_t)(b * 3 + ci)) << 14) + (gy << 7) + gx];
        tile[ci * 1156 + rem] = v;
    }
    __syncthreads();

    const int ty = tid >> 4, tx = tid & 15, py = ty * 2;
    float acc[2][2][8];
    #pragma unroll
    for (int r = 0; r < 2; ++r)
        #pragma unroll
        for (int h = 0; h < 2; ++h)
            #pragma unroll
            for (int co = 0; co < 8; ++co) acc[r][h][co] = 0.f;

    #pragma unroll
    for (int ci = 0; ci < 3; ++ci) {
        #pragma unroll
        for (int ky = 0; ky < 3; ++ky) {
            #pragma unroll
            for (int kx = 0; kx < 3; ++kx) {
                const float* wp = wlds + (ci * 9 + ky * 3 + kx) * 8;
                float i00 = tile[ci * 1156 + (py + ky) * 34 + tx + kx];
                float i01 = tile[ci * 1156 + (py + ky) * 34 + tx + 16 + kx];
                float i10 = tile[ci * 1156 + (py + 1 + ky) * 34 + tx + kx];
                float i11 = tile[ci * 1156 + (py + 1 + ky) * 34 + tx + 16 + kx];
                #pragma unroll
                for (int co = 0; co < 8; ++co) {
                    float wv = wp[co];
                    acc[0][0][co] += i00 * wv;
                    acc[0][1][co] += i01 * wv;
                    acc[1][0][co] += i10 * wv;
                    acc[1][1][co] += i11 * wv;
                }
            }
        }
    }

    #pragma unroll
    for (int r = 0; r < 2; ++r) {
        #pragma unroll
        for (int h = 0; h < 2; ++h) {
            int gy = tile_y + py + r, gx = tile_x + tx + h * 16;
            bf16x8 pv;
            #pragma unroll
            for (int co = 0; co < 8; ++co)
                pv[co] = (short)f2bf(acc[r][h][co] + bh[cog * 8 + co]);
            *(bf16x8*)(fb0 + (((((size_t)b << 14) + gy * 128 + gx)) << 7) + cog * 8) = pv;
        }
    }
}

// ---------------- main conv: implicit GEMM, bf16 MFMA (R14 EXACT) -----------
// Block: 16x16 px tile; A staged in two 64-ch halves, UNPADDED stride 64 ush
// with XOR swizzle (channel-group p = g ^ (px&7)) -> conflict-free b128 reads.
// WNSPLIT=1: 4 waves tile 2 m-groups x 2 n-groups (LM=8, NTW=4 for 128 co).
template <int LM, int NTW, int WNSPLIT, int DOMEAN>
__global__ __launch_bounds__(256, 2) void conv_mfma(
    const unsigned short* __restrict__ in, const unsigned short* __restrict__ wT,
    size_t wstride, const float* __restrict__ bias, unsigned short* __restrict__ out,
    float* __restrict__ meanb, const float* __restrict__ x,
    const unsigned short* __restrict__ kb, float* __restrict__ outf,
    int Coutp, int Cout, int relu)
{
    __shared__ unsigned short lds[20736];
    const int tid = threadIdx.x;
    const int b = blockIdx.y;
    const int row0 = (blockIdx.x >> 3) << 4;
    const int col0 = (blockIdx.x & 7) << 4;
    const int l = tid & 63, wv = tid >> 6;
    const int li = l & 15, lq = l >> 4;
    const int m_base = WNSPLIT ? (wv >> 1) * LM : wv * LM;
    const int n_base = WNSPLIT ? (wv & 1) * NTW : 0;
    const size_t inb = ((size_t)b) << 14;
    const unsigned short* wbase = wT + (size_t)b * wstride;

    f32x4 acc[LM][NTW];
    #pragma unroll
    for (int lm = 0; lm < LM; ++lm)
        #pragma unroll
        for (int nt = 0; nt < NTW; ++nt)
            acc[lm][nt] = (f32x4){0.f, 0.f, 0.f, 0.f};

    #pragma unroll 1
    for (int half = 0; half < 2; ++half) {
        __syncthreads();
        for (int u = tid; u < 2592; u += 256) {   // 324 px * 8 ch-groups
            int px = u >> 3, g = u & 7;
            int hr = px / 18, hc = px - hr * 18;
            int gy = row0 - 1 + hr, gx = col0 - 1 + hc;
            bf16x8 v = {0, 0, 0, 0, 0, 0, 0, 0};
            if ((unsigned)gy < 128u && (unsigned)gx < 128u)
                v = *(const bf16x8*)(in + ((inb + (gy << 7) + gx) << 7) + half * 64 + g * 8);
            int p = g ^ (px & 7);                 // XOR swizzle
            *(bf16x8*)(lds + px * 64 + p * 8) = v;
        }
        __syncthreads();

        auto loadB = [&](bf16x8 (&dst)[NTW], int s) {
            int tap = s >> 1, kcl = s & 1;
            const unsigned short* p = wbase +
                (size_t)(tap * 4 + half * 2 + kcl) * (Coutp * 32) +
                (n_base * 16 + li) * 32 + lq * 8;
            #pragma unroll
            for (int nt = 0; nt < NTW; ++nt)
                dst[nt] = *(const bf16x8*)(p + nt * 512);
        };
        auto compute = [&](bf16x8 (&bf)[NTW], int s) {
            int tap = s >> 1, kcl = s & 1;
            int ky = tap / 3, kx = tap - ky * 3;
            int g = kcl * 4 + lq;
            #pragma unroll
            for (int lm = 0; lm < LM; ++lm) {
                int px = (m_base + lm + ky) * 18 + li + kx;
                bf16x8 af = *(const bf16x8*)(lds + px * 64 + ((g ^ (px & 7)) * 8));
                #pragma unroll
                for (int nt = 0; nt < NTW; ++nt)
                    acc[lm][nt] = __builtin_amdgcn_mfma_f32_16x16x32_bf16(
                        af, bf[nt], acc[lm][nt], 0, 0, 0);
            }
        };

        bf16x8 bufA[NTW], bufB[NTW];
        loadB(bufA, 0);
        #pragma unroll 1
        for (int it = 0; it < 18; it += 2) {
            loadB(bufB, it + 1);
            compute(bufA, it);
            if (it + 2 < 18) loadB(bufA, it + 2);
            compute(bufB, it + 1);
        }
    }

    float bv[NTW], msum[NTW];
    #pragma unroll
    for (int nt = 0; nt < NTW; ++nt) {
        int co = (n_base + nt) * 16 + li;
        bv[nt] = (co < Cout) ? bias[co] : 0.f;
        msum[nt] = 0.f;
    }

    #pragma unroll
    for (int lm = 0; lm < LM; ++lm) {
        int row = row0 + m_base + lm;
        #pragma unroll
        for (int r = 0; r < 4; ++r) {
            int col = col0 + lq * 4 + r;
            size_t pbase = (inb + row * 128 + col) * (size_t)Coutp;
            #pragma unroll
            for (int nt = 0; nt < NTW; ++nt) {
                float v = acc[lm][nt][r] + bv[nt];
                if (relu) v = fmaxf(v, 0.f);
                if (DOMEAN) msum[nt] += v;
                out[pbase + (n_base + nt) * 16 + li] = f2bf(v);
            }
        }
    }
    if (DOMEAN) {
        #pragma unroll
        for (int nt = 0; nt < NTW; ++nt) {
            float t = msum[nt];
            t += __shfl_xor(t, 16, 64);
            t += __shfl_xor(t, 32, 64);
            if (lq == 0)
                atomicAdd(&meanb[b * 128 + (n_base + nt) * 16 + li], t);
        }
    }
}

// ---------------- SE-scaled conv (separate function: codegen decoupled) -----
// SCALEA hardwired: sl[128] per-block prologue (wave-parallel), applied
// during A staging. TAILFUSE: dynfilter fusion (MFMA e-GEMM), final output.
template <int LM, int NTW, int WNSPLIT, int DOMEAN, int TAILFUSE>
__global__ __launch_bounds__(256, 2) void conv_mfma_se(
    const unsigned short* __restrict__ in, const unsigned short* __restrict__ wT,
    const float* __restrict__ bias, unsigned short* __restrict__ out,
    float* __restrict__ meanb, const float* __restrict__ se_mean,
    const float* __restrict__ sw1, const float* __restrict__ sb1,
    const float* __restrict__ sw2, const float* __restrict__ sb2,
    const float* __restrict__ x, const unsigned short* __restrict__ kb,
    float* __restrict__ outf, int Coutp, int Cout, int relu)
{
    __shared__ unsigned short lds[TAILFUSE ? 26624 : 20736];
    __shared__ float slds[136];          // [0:128) sigmoid scales, [128:136) h1
    const int tid = threadIdx.x;
    const int b = blockIdx.y;
    const int row0 = (blockIdx.x >> 3) << 4;
    const int col0 = (blockIdx.x & 7) << 4;
    const int l = tid & 63, wv = tid >> 6;
    const int li = l & 15, lq = l >> 4;
    const int m_base = WNSPLIT ? (wv >> 1) * LM : wv * LM;
    const int n_base = WNSPLIT ? (wv & 1) * NTW : 0;
    const size_t inb = ((size_t)b) << 14;
    const unsigned short* wbase = wT;

    // ---- wave-parallel SE prologue: 8 groups of 32 lanes, one dot each ----
    {
        const int grp = tid >> 5, j = tid & 31;
        float4 wv4 = ((const float4*)(sw1 + grp * 128))[j];
        float4 mv4 = ((const float4*)(se_mean + b * 128))[j];
        float part = wv4.x * mv4.x + wv4.y * mv4.y + wv4.z * mv4.z + wv4.w * mv4.w;
        part += __shfl_xor(part, 1, 64);
        part += __shfl_xor(part, 2, 64);
        part += __shfl_xor(part, 4, 64);
        part += __shfl_xor(part, 8, 64);
        part += __shfl_xor(part, 16, 64);
        if (j == 0)
            slds[128 + grp] = fmaxf(part * (1.f / 16384.f) + sb1[grp], 0.f);
    }
    __syncthreads();
    if (tid < 128) {
        float s = sb2[tid];
        #pragma unroll
        for (int j = 0; j < 8; ++j) s += sw2[tid * 8 + j] * slds[128 + j];
        slds[tid] = 1.f / (1.f + expf(-s));
    }
    __syncthreads();

    f32x4 acc[LM][NTW];
    #pragma unroll
    for (int lm = 0; lm < LM; ++lm)
        #pragma unroll
        for (int nt = 0; nt < NTW; ++nt)
            acc[lm][nt] = (f32x4){0.f, 0.f, 0.f, 0.f};

    #pragma unroll 1
    for (int half = 0; half < 2; ++half) {
        float msc[8];
        #pragma unroll
        for (int j = 0; j < 8; ++j)
            msc[j] = slds[half * 64 + (tid & 7) * 8 + j];
        __syncthreads();
        for (int u = tid; u < 2592; u += 256) {   // 324 px * 8 ch-groups
            int px = u >> 3, g = u & 7;
            int hr = px / 18, hc = px - hr * 18;
            int gy = row0 - 1 + hr, gx = col0 - 1 + hc;
            bf16x8 v = {0, 0, 0, 0, 0, 0, 0, 0};
            if ((unsigned)gy < 128u && (unsigned)gx < 128u)
                v = *(const bf16x8*)(in + ((inb + (gy << 7) + gx) << 7) + half * 64 + g * 8);
            #pragma unroll
            for (int j = 0; j < 8; ++j)
                v[j] = (short)f2bf(bf2f((unsigned short)v[j]) * msc[j]);
            int p = g ^ (px & 7);                 // XOR swizzle
            *(bf16x8*)(lds + px * 64 + p * 8) = v;
        }
        __syncthreads();

        auto loadB = [&](bf16x8 (&dst)[NTW], int s) {
            int tap = s >> 1, kcl = s & 1;
            const unsigned short* p = wbase +
                (size_t)(tap * 4 + half * 2 + kcl) * (Coutp * 32) +
                (n_base * 16 + li) * 32 + lq * 8;
            #pragma unroll
            for (int nt = 0; nt < NTW; ++nt)
                dst[nt] = *(const bf16x8*)(p + nt * 512);
        };
        auto compute = [&](bf16x8 (&bf)[NTW], int s) {
            int tap = s >> 1, kcl = s & 1;
            int ky = tap / 3, kx = tap - ky * 3;
            int g = kcl * 4 + lq;
            #pragma unroll
            for (int lm = 0; lm < LM; ++lm) {
                int px = (m_base + lm + ky) * 18 + li + kx;
                bf16x8 af = *(const bf16x8*)(lds + px * 64 + ((g ^ (px & 7)) * 8));
                #pragma unroll
                for (int nt = 0; nt < NTW; ++nt)
                    acc[lm][nt] = __builtin_amdgcn_mfma_f32_16x16x32_bf16(
                        af, bf[nt], acc[lm][nt], 0, 0, 0);
            }
        };

        bf16x8 bufA[NTW], bufB[NTW];
        loadB(bufA, 0);
        #pragma unroll 1
        for (int it = 0; it < 18; it += 2) {
            loadB(bufB, it + 1);
            compute(bufA, it);
            if (it + 2 < 18) loadB(bufA, it + 2);
            compute(bufB, it + 1);
        }
    }

    float bv[NTW], msum[NTW];
    #pragma unroll
    for (int nt = 0; nt < NTW; ++nt) {
        int co = (n_base + nt) * 16 + li;
        bv[nt] = (co < Cout) ? bias[co] : 0.f;
        msum[nt] = 0.f;
    }

    if (TAILFUSE) {
        // ---- P (wgt) -> LDS, stride 104 ush; zero pad co 80..95 ----
        __syncthreads();
        #pragma unroll
        for (int lm = 0; lm < LM; ++lm) {
            int rowl = m_base + lm;
            #pragma unroll
            for (int r = 0; r < 4; ++r) {
                int coll = lq * 4 + r;
                #pragma unroll
                for (int nt = 0; nt < NTW; ++nt)
                    lds[(rowl * 16 + coll) * 104 + nt * 16 + li] =
                        f2bf(acc[lm][nt][r] + bv[nt]);
            }
        }
        {
            bf16x8 z = {0, 0, 0, 0, 0, 0, 0, 0};
            *(bf16x8*)(lds + tid * 104 + 80) = z;
            *(bf16x8*)(lds + tid * 104 + 88) = z;
        }
        __syncthreads();

        // ---- e-GEMM: e[px][i] = sum_co P[px][co] * kern[co][i] ----
        f32x4 eacc[4][2];
        #pragma unroll
        for (int mm = 0; mm < 4; ++mm)
            #pragma unroll
            for (int nt = 0; nt < 2; ++nt)
                eacc[mm][nt] = (f32x4){0.f, 0.f, 0.f, 0.f};
        #pragma unroll
        for (int s = 0; s < 3; ++s) {
            bf16x8 kbf[2];
            #pragma unroll
            for (int nt = 0; nt < 2; ++nt)
                kbf[nt] = *(const bf16x8*)(kb + ((s * 2 + nt) * 16 + li) * 32 + lq * 8);
            #pragma unroll
            for (int mm = 0; mm < 4; ++mm) {
                int px = (wv * 4 + mm) * 16 + li;
                bf16x8 pf = *(const bf16x8*)(lds + px * 104 + s * 32 + lq * 8);
                #pragma unroll
                for (int nt = 0; nt < 2; ++nt)
                    eacc[mm][nt] = __builtin_amdgcn_mfma_f32_16x16x32_bf16(
                        pf, kbf[nt], eacc[mm][nt], 0, 0, 0);
            }
        }
        __syncthreads();

        // ---- e (C-layout) -> LDS fp32, stride 33 ----
        float* elds = (float*)lds;
        #pragma unroll
        for (int mm = 0; mm < 4; ++mm) {
            #pragma unroll
            for (int nt = 0; nt < 2; ++nt) {
                int i = nt * 16 + li;
                if (i < 25) {
                    #pragma unroll
                    for (int r = 0; r < 4; ++r) {
                        int px = (wv * 4 + mm) * 16 + lq * 4 + r;
                        elds[px * 33 + i] = eacc[mm][nt][r];
                    }
                }
            }
        }
        __syncthreads();

        // ---- apply ----
        const int h = row0 + (tid >> 4), w = col0 + (tid & 15);
        const int pix = h * 128 + w;
        float e[25];
        #pragma unroll
        for (int i = 0; i < 25; ++i) e[i] = elds[tid * 33 + i];

        int yy[5], xx[5];
        #pragma unroll
        for (int d = 0; d < 5; ++d) {
            int y = h - 2 + d;
            yy[d] = y < 0 ? -y : (y > 127 ? 254 - y : y);
            int xv = w - 2 + d;
            xx[d] = xv < 0 ? -xv : (xv > 127 ? 254 - xv : xv);
        }
        #pragma unroll
        for (int c = 0; c < 3; ++c) {
            const float* xc = x + ((size_t)(b * 3 + c) << 14);
            float s = 0.f;
            #pragma unroll
            for (int dy = 0; dy < 5; ++dy)
                #pragma unroll
                for (int dx = 0; dx < 5; ++dx)
                    s += e[dy * 5 + dx] * xc[yy[dy] * 128 + xx[dx]];
            outf[((size_t)(b * 3 + c) << 14) + pix] = s;
        }
        return;
    }

    #pragma unroll
    for (int lm = 0; lm < LM; ++lm) {
        int row = row0 + m_base + lm;
        #pragma unroll
        for (int r = 0; r < 4; ++r) {
            int col = col0 + lq * 4 + r;
            size_t pbase = (inb + row * 128 + col) * (size_t)Coutp;
            #pragma unroll
            for (int nt = 0; nt < NTW; ++nt) {
                float v = acc[lm][nt][r] + bv[nt];
                if (relu) v = fmaxf(v, 0.f);
                if (DOMEAN) msum[nt] += v;
                out[pbase + (n_base + nt) * 16 + li] = f2bf(v);
            }
        }
    }
    if (DOMEAN) {
        #pragma unroll
        for (int nt = 0; nt < NTW; ++nt) {
            float t = msum[nt];
            t += __shfl_xor(t, 16, 64);
            t += __shfl_xor(t, 32, 64);
            if (lq == 0)
                atomicAdd(&meanb[b * 128 + (n_base + nt) * 16 + li], t);
        }
    }
}

// ---------------------------------------------------------------------------
extern "C" void kernel_launch(void* const* d_in, const int* in_sizes, int n_in,
                              void* d_out, int out_size, void* d_ws, size_t ws_size,
                              hipStream_t stream)
{
    const float* x      = (const float*)d_in[0];
    const float* w_head = (const float*)d_in[1];
    const float* b_head = (const float*)d_in[2];
    const float* w_h1a  = (const float*)d_in[3];
    const float* b_h1a  = (const float*)d_in[4];
    const float* w_h1b  = (const float*)d_in[5];
    const float* b_h1b  = (const float*)d_in[6];
    const float* du1_w1 = (const float*)d_in[7];
    const float* du1_b1 = (const float*)d_in[8];
    const float* du1_w2 = (const float*)d_in[9];
    const float* du1_b2 = (const float*)d_in[10];
    const float* w_h2a  = (const float*)d_in[11];
    const float* b_h2a  = (const float*)d_in[12];
    const float* w_h2b  = (const float*)d_in[13];
    const float* b_h2b  = (const float*)d_in[14];
    const float* du2_w1 = (const float*)d_in[15];
    const float* du2_b1 = (const float*)d_in[16];
    const float* du2_w2 = (const float*)d_in[17];
    const float* du2_b2 = (const float*)d_in[18];
    const float* w_tail = (const float*)d_in[19];
    const float* b_tail = (const float*)d_in[20];
    const float* kern   = (const float*)d_in[21];
    float* out = (float*)d_out;

    unsigned short* fb0  = (unsigned short*)d_ws;        // 16,777,216 elems
    unsigned short* fb1  = fb0 + 16777216;
    unsigned short* wt1  = fb1 + 16777216;               // 147456 each
    unsigned short* wt2  = wt1 + 147456;
    unsigned short* wt3  = wt2 + 147456;
    unsigned short* wt4  = wt3 + 147456;
    unsigned short* wtt  = wt4 + 147456;                 // 92160
    unsigned short* kbb  = wtt + 92160;                  // 3072 (kern B-frag)
    float* mean1  = (float*)(kbb + 3072);                // 1024
    float* mean2  = mean1 + 1024;

    dim3 blk(256);
    // prep: head conv (2048) + coalesced wtrans (74) + kb/means (1)
    prep<<<dim3(2123), blk, 0, stream>>>(x, w_head, b_head, fb0,
                                         w_h1a, w_h1b, w_h2a, w_h2b, w_tail,
                                         kern, wt1, wt2, wt3, wt4, wtt, kbb,
                                         mean1);

    dim3 cgrid(64, 8);   // 512 blocks: 64 tiles/batch x 8 batches
    conv_mfma<8, 4, 1, 0><<<cgrid, blk, 0, stream>>>(
        fb0, wt1, 0, b_h1a, fb1, nullptr, nullptr, nullptr, nullptr, 128, 128, 1);
    conv_mfma<8, 4, 1, 1><<<cgrid, blk, 0, stream>>>(
        fb1, wt2, 0, b_h1b, fb0, mean1, nullptr, nullptr, nullptr, 128, 128, 1);

    // h2a: SE1 scale applied to staged A (reads mean1 + du1 params)
    conv_mfma_se<8, 4, 1, 0, 0><<<cgrid, blk, 0, stream>>>(
        fb0, wt3, b_h2a, fb1, nullptr, mean1, du1_w1, du1_b1, du1_w2, du1_b2,
        nullptr, nullptr, nullptr, 128, 128, 1);
    conv_mfma<8, 4, 1, 1><<<cgrid, blk, 0, stream>>>(
        fb1, wt4, 0, b_h2b, fb0, mean2, nullptr, nullptr, nullptr, 128, 128, 1);

    // tail conv (SE2 scale on staged A) + fused dynamic filter e-GEMM
    conv_mfma_se<4, 5, 0, 0, 1><<<cgrid, blk, 0, stream>>>(
        fb0, wtt, b_tail, nullptr, nullptr, mean2, du2_w1, du2_b1, du2_w2,
        du2_b2, x, kbb, out, 80, 72, 0);
}